// Round 11
// baseline (844.529 us; speedup 1.0000x reference)
//
#include <hip/hip_runtime.h>
#include <hip/hip_fp16.h>
#include <cstddef>

#define NA 200000
#define NE 3200000
#define NB 512
#define NBKT 256          // dst-range buckets
#define BKTN 782          // nodes per bucket
#define BKTCAP 16384      // stage capacity per bucket (exp 12500, sigma ~111)
#define NEPB 3200         // edges per pass-1 block (1000*3200 = NE)

// ---------------- fp16 helpers ----------------
union UH2 { unsigned u; __half2 h; };
__device__ __forceinline__ float4 h4f(unsigned a, unsigned b) {
    UH2 x, y; x.u = a; y.u = b;
    float2 fa = __half22float2(x.h), fb = __half22float2(y.h);
    return make_float4(fa.x, fa.y, fb.x, fb.y);
}
__device__ __forceinline__ unsigned f2h(float a, float b) {
    UH2 r; r.h = __float22half2_rn(make_float2(a, b));
    return r.u;
}

// ---------------- init: g=0, gcursor[b]=b*BKTCAP ----------------
__global__ void k_init(unsigned* g, int* gcursor) {
    int i = blockIdx.x * blockDim.x + threadIdx.x;
    if (i < NB * 16) g[i] = 0u;
    if (i < NBKT) gcursor[i] = i * BKTCAP;
}

// ---------------- conv1 device body (untiled, transpose load) --------------
template<int CIN, int COUT, int OBLK, int LIN, int PITCH, int POUT, int NTT>
__device__ __forceinline__ void dev_conv1(int b, int oy,
        const float* __restrict__ in, const float* __restrict__ Kw,
        const float* __restrict__ bias, float* __restrict__ out) {
    constexpr int SPO = 256 / OBLK;
    constexpr int PT = (NTT < 4) ? NTT : 4;
    constexpr int NPASS = (NTT + PT - 1) / PT;
    __shared__ __align__(16) float s_in[CIN * PITCH];
    for (int idx = threadIdx.x; idx < CIN * PITCH; idx += 256) s_in[idx] = 0.f;
    __syncthreads();
    for (int idx = threadIdx.x; idx < LIN * CIN; idx += 256) {
        int p = idx / CIN, c = idx - p * CIN;
        s_in[c * PITCH + p] = in[(size_t)b * (LIN * CIN) + idx];
    }
    __syncthreads();
    int ol = threadIdx.x / SPO;
    int s  = threadIdx.x - ol * SPO;
    int o  = oy * OBLK + ol;
    float bo = bias[o];
    const float* wrow = Kw + (size_t)o * CIN * 8;
    for (int pass = 0; pass < NPASS; pass++) {
        float acc[PT][12];
#pragma unroll
        for (int tt = 0; tt < PT; tt++)
#pragma unroll
            for (int j = 0; j < 12; j++) acc[tt][j] = 0.f;
        bool vld[PT]; int tgs[PT];
#pragma unroll
        for (int tt = 0; tt < PT; tt++) {
            int ta = pass * PT + tt;
            int tg = s + SPO * ta;
            tgs[tt] = tg;
            vld[tt] = (ta < NTT) && (4 * tg < POUT);
        }
        for (int i = 0; i < CIN; i++) {
            float wa[8];
            const float4* wp = (const float4*)(wrow + (size_t)i * 8);
            *(float4*)&wa[0] = wp[0];
            *(float4*)&wa[4] = wp[1];
#pragma unroll
            for (int tt = 0; tt < PT; tt++) {
                if (vld[tt]) {
                    const float4* xr = (const float4*)&s_in[i * PITCH + 12 * tgs[tt]];
                    float xa[20];
#pragma unroll
                    for (int q = 0; q < 5; q++) *(float4*)&xa[4 * q] = xr[q];
#pragma unroll
                    for (int j = 0; j < 12; j++) {
                        float sm = acc[tt][j];
#pragma unroll
                        for (int k = 0; k < 8; k++) sm = fmaf(xa[j + k], wa[k], sm);
                        acc[tt][j] = sm;
                    }
                }
            }
        }
#pragma unroll
        for (int tt = 0; tt < PT; tt++) {
            if (vld[tt]) {
#pragma unroll
                for (int p = 0; p < 4; p++) {
                    int P = 4 * tgs[tt] + p;
                    if (P < POUT) {
                        float m = fmaxf(fmaxf(acc[tt][3 * p], acc[tt][3 * p + 1]), acc[tt][3 * p + 2]);
                        out[((size_t)b * COUT + o) * POUT + P] = fmaxf(m + bo, 0.f);
                    }
                }
            }
        }
    }
}

// ------------- tiled conv device body (seq-axis tiles, small LDS) ----------
template<int CIN, int COUT, int OBLK, int LIN, int PITCH, int TPOOL, int POUT>
__device__ __forceinline__ void dev_conv_t(int b, int oy, int tile,
        const float* __restrict__ in, const float* __restrict__ Kw,
        const float* __restrict__ bias, float* __restrict__ out) {
    constexpr int SPO = 256 / OBLK;
    constexpr int NQ = TPOOL / 4;
    constexpr int NTT = (NQ + SPO - 1) / SPO;
    constexpr int SPAN = 3 * TPOOL + 7;
    __shared__ __align__(16) float s_in[CIN * PITCH];
    int p0 = tile * TPOOL;
    int cbase = 3 * p0;
    for (int idx = threadIdx.x; idx < CIN * PITCH; idx += 256) {
        int c = idx / PITCH, p = idx - c * PITCH;
        int gp = cbase + p;
        float v = 0.f;
        if (p < SPAN && gp < LIN) v = in[((size_t)b * CIN + c) * LIN + gp];
        s_in[idx] = v;
    }
    __syncthreads();
    int ol = threadIdx.x / SPO;
    int s  = threadIdx.x - ol * SPO;
    int o  = oy * OBLK + ol;
    float bo = bias[o];
    const float* wrow = Kw + (size_t)o * CIN * 8;
    float acc[NTT][12];
#pragma unroll
    for (int tt = 0; tt < NTT; tt++)
#pragma unroll
        for (int j = 0; j < 12; j++) acc[tt][j] = 0.f;
    bool vld[NTT]; int qgs[NTT];
#pragma unroll
    for (int tt = 0; tt < NTT; tt++) {
        int qg = s + SPO * tt;
        qgs[tt] = qg;
        vld[tt] = (qg < NQ) && (p0 + 4 * qg < POUT);
    }
    for (int i = 0; i < CIN; i++) {
        float wa[8];
        const float4* wp = (const float4*)(wrow + (size_t)i * 8);
        *(float4*)&wa[0] = wp[0];
        *(float4*)&wa[4] = wp[1];
#pragma unroll
        for (int tt = 0; tt < NTT; tt++) {
            if (vld[tt]) {
                const float4* xr = (const float4*)&s_in[i * PITCH + 12 * qgs[tt]];
                float xa[20];
#pragma unroll
                for (int q = 0; q < 5; q++) *(float4*)&xa[4 * q] = xr[q];
#pragma unroll
                for (int j = 0; j < 12; j++) {
                    float sm = acc[tt][j];
#pragma unroll
                    for (int k = 0; k < 8; k++) sm = fmaf(xa[j + k], wa[k], sm);
                    acc[tt][j] = sm;
                }
            }
        }
    }
#pragma unroll
    for (int tt = 0; tt < NTT; tt++) {
        if (vld[tt]) {
#pragma unroll
            for (int p = 0; p < 4; p++) {
                int P = p0 + 4 * qgs[tt] + p;
                if (P < POUT) {
                    float m = fmaxf(fmaxf(acc[tt][3 * p], acc[tt][3 * p + 1]), acc[tt][3 * p + 2]);
                    out[((size_t)b * COUT + o) * POUT + P] = fmaxf(m + bo, 0.f);
                }
            }
        }
    }
}

// -------- K_A: pass1 edge binning (1000) || conv1 (1024) -------------------
__global__ __launch_bounds__(256) void k_A(
        const int* __restrict__ src, const int* __restrict__ dst,
        int* __restrict__ gcursor, unsigned* __restrict__ stage,
        const float* __restrict__ tgt, const float* __restrict__ K1,
        const float* __restrict__ cb1, float* __restrict__ pool1) {
    __shared__ int hcnt[NBKT];
    __shared__ int hbase[NBKT];
    int bx = blockIdx.x;
    if (bx >= 1000) {
        int id = bx - 1000;
        dev_conv1<5, 32, 16, 1000, 1008, 331, 6>(id & 511, id >> 9, tgt, K1, cb1, pool1);
        return;
    }
    int e0 = bx * NEPB;
    hcnt[threadIdx.x] = 0;
    __syncthreads();
    const int4* d4 = (const int4*)(dst + e0);
    for (int i = threadIdx.x; i < NEPB / 4; i += 256) {
        int4 d = d4[i];
        atomicAdd(&hcnt[d.x / BKTN], 1);
        atomicAdd(&hcnt[d.y / BKTN], 1);
        atomicAdd(&hcnt[d.z / BKTN], 1);
        atomicAdd(&hcnt[d.w / BKTN], 1);
    }
    __syncthreads();
    hbase[threadIdx.x] = atomicAdd(&gcursor[threadIdx.x], hcnt[threadIdx.x]);
    hcnt[threadIdx.x] = 0;
    __syncthreads();
    const int4* s4 = (const int4*)(src + e0);
    for (int i = threadIdx.x; i < NEPB / 4; i += 256) {
        int4 d = d4[i];
        int4 s = s4[i];
        int ds[4] = {d.x, d.y, d.z, d.w};
        int ss[4] = {s.x, s.y, s.z, s.w};
#pragma unroll
        for (int j = 0; j < 4; j++) {
            int bkt = ds[j] / BKTN;
            int dloc = ds[j] - bkt * BKTN;
            int k = atomicAdd(&hcnt[bkt], 1);
            stage[hbase[bkt] + k] = ((unsigned)dloc << 18) | (unsigned)ss[j];
        }
    }
}

// -------- K_B: pass2 (256) || conv2 tiled (1536) ---------------------------
// pass2: per-bucket count+scan+scatter -> compact CSR; emits dt1 = dis*x
__global__ __launch_bounds__(256) void k_B(
        const unsigned* __restrict__ stage, const int* __restrict__ gcursor,
        int* __restrict__ rowptr, int* __restrict__ cnt, int* __restrict__ csr,
        const float* __restrict__ x, float4* __restrict__ dt1,
        const float* __restrict__ pool1, const float* __restrict__ K2,
        const float* __restrict__ cb2, float* __restrict__ pool2) {
    __shared__ int lcnt[BKTN];
    __shared__ int lpos[BKTN];
    __shared__ int partial[256];
    __shared__ int sbase;
    int bx = blockIdx.x;
    if (bx >= NBKT) {
        int id = bx - NBKT;
        dev_conv_t<32, 64, 64, 331, 116, 36, 108>(id & 511, 0, id >> 9, pool1, K2, cb2, pool2);
        return;
    }
    int t = threadIdx.x;
    int bkt = bx;
    int tot = gcursor[t] - t * BKTCAP;
    partial[t] = tot;
    __syncthreads();
#pragma unroll
    for (int off = 1; off < 256; off <<= 1) {
        int u = (t >= off) ? partial[t - off] : 0;
        __syncthreads();
        partial[t] += u;
        __syncthreads();
    }
    if (t == 0) sbase = (bkt == 0) ? 0 : partial[bkt - 1];
    __syncthreads();
    int base = sbase;
    int n0 = bkt * BKTN;
    int ncnt = (NA - n0 < BKTN) ? (NA - n0) : BKTN;
    int eBeg = bkt * BKTCAP;
    int eCnt = gcursor[bkt] - eBeg;
    for (int i = t; i < BKTN; i += 256) lcnt[i] = 0;
    __syncthreads();
    for (int i = t; i < eCnt; i += 256)
        atomicAdd(&lcnt[stage[eBeg + i] >> 18], 1);
    __syncthreads();
    int mysum = 0;
#pragma unroll
    for (int j = 0; j < 4; j++) {
        int node = 4 * t + j;
        if (node < ncnt) mysum += lcnt[node];
    }
    partial[t] = mysum;
    __syncthreads();
#pragma unroll
    for (int off = 1; off < 256; off <<= 1) {
        int u = (t >= off) ? partial[t - off] : 0;
        __syncthreads();
        partial[t] += u;
        __syncthreads();
    }
    int running = partial[t] - mysum;
#pragma unroll
    for (int j = 0; j < 4; j++) {
        int node = 4 * t + j;
        if (node < ncnt) {
            lpos[node] = running;
            rowptr[n0 + node] = base + running;
            cnt[n0 + node] = lcnt[node];
            running += lcnt[node];
        }
    }
    __syncthreads();
    for (int i = t; i < eCnt; i += 256) {
        unsigned v = stage[eBeg + i];
        int dloc = v >> 18;
        int s = v & 0x3FFFF;
        int k = atomicAdd(&lpos[dloc], 1);
        csr[base + k] = s;
    }
    for (int i = t; i < ncnt; i += 256) {
        int n = n0 + i;
        float4 p = ((const float4*)x)[n];
        float dv = rsqrtf((float)lcnt[i] + 1.0f);
        dt1[n] = make_float4(dv * p.x, dv * p.y, dv * p.z, dv * p.w);
    }
}

// -------- K_C: gather1+W1 -> dt2 (782) || conv3 tiled (1024) ---------------
__global__ __launch_bounds__(256) void k_C(
        const float* __restrict__ pool2, const float* __restrict__ K3,
        const float* __restrict__ cb3, float* __restrict__ pool3,
        const float4* __restrict__ dt1, const int* __restrict__ rowptr,
        const int* __restrict__ cnt, const int* __restrict__ csr,
        const float* __restrict__ W1, const float* __restrict__ b1,
        float4* __restrict__ dt2) {
    int bx = blockIdx.x;
    if (bx >= 782) {
        int id = bx - 782;
        dev_conv_t<64, 128, 128, 108, 68, 20, 33>(id & 511, 0, id >> 9, pool2, K3, cb3, pool3);
        return;
    }
    __shared__ float sW[16];
    if (threadIdx.x < 16) sW[threadIdx.x] = W1[threadIdx.x];
    __syncthreads();
    int n = bx * 256 + threadIdx.x;
    if (n >= NA) return;
    int cn = cnt[n];
    float dv = rsqrtf((float)cn + 1.0f);
    const int* row = csr + rowptr[n];
    float4 acc = dt1[n];
    int e = 0;
    for (; e + 3 < cn; e += 4) {
        int i0 = row[e], i1 = row[e + 1], i2 = row[e + 2], i3 = row[e + 3];
        float4 v0 = dt1[i0], v1 = dt1[i1], v2 = dt1[i2], v3 = dt1[i3];
        acc.x += (v0.x + v1.x) + (v2.x + v3.x);
        acc.y += (v0.y + v1.y) + (v2.y + v3.y);
        acc.z += (v0.z + v1.z) + (v2.z + v3.z);
        acc.w += (v0.w + v1.w) + (v2.w + v3.w);
    }
    for (; e < cn; e++) {
        float4 v = dt1[row[e]];
        acc.x += v.x; acc.y += v.y; acc.z += v.z; acc.w += v.w;
    }
    const float4 bq = *(const float4*)b1;
    float a[4] = {acc.x, acc.y, acc.z, acc.w};
    float bb[4] = {bq.x, bq.y, bq.z, bq.w};
    float o[4];
#pragma unroll
    for (int f = 0; f < 4; f++) {
        float s = 0.f;
#pragma unroll
        for (int k = 0; k < 4; k++) s = fmaf(a[k], sW[k * 4 + f], s);
        o[f] = dv * fmaxf(fmaf(dv, s, bb[f]), 0.f);   // dt2 = dv*relu(...)
    }
    dt2[n] = make_float4(o[0], o[1], o[2], o[3]);
}

// -------- K_D: gather2+W2 -> dt3 fp16 (782) || mean+Wxt -> cx (64) ---------
__global__ __launch_bounds__(256) void k_D(
        const float4* __restrict__ dt2, const int* __restrict__ rowptr,
        const int* __restrict__ cnt, const int* __restrict__ csr,
        const float* __restrict__ W2, const float* __restrict__ b2,
        uint4* __restrict__ dt3,
        const float* __restrict__ pool3, const float* __restrict__ Wxt,
        const float* __restrict__ bxt, float* __restrict__ cx) {
    int bx = blockIdx.x;
    if (bx >= 782) {
        // mean over 33 taps then @Wxt (+relu): 8 batches/block
        __shared__ float sa[8 * 128];
        int b0 = (bx - 782) * 8;
        for (int t = threadIdx.x; t < 8 * 128; t += 256) {
            int gg = t >> 7, k = t & 127;
            const float* r = pool3 + ((size_t)(b0 + gg) * 128 + k) * 33;
            float s = 0.f;
#pragma unroll
            for (int p = 0; p < 33; p++) s += r[p];
            sa[t] = s * (1.f / 33.f);
        }
        __syncthreads();
        int j = threadIdx.x;
        if (j >= 128) return;
        float bj = bxt[j];
        float acc[8];
#pragma unroll
        for (int gg = 0; gg < 8; gg++) acc[gg] = bj;
#pragma unroll 4
        for (int k = 0; k < 128; k++) {
            float w = Wxt[(size_t)k * 128 + j];
#pragma unroll
            for (int gg = 0; gg < 8; gg++) acc[gg] = fmaf(sa[gg * 128 + k], w, acc[gg]);
        }
#pragma unroll
        for (int gg = 0; gg < 8; gg++)
            cx[(size_t)(b0 + gg) * 128 + j] = fmaxf(acc[gg], 0.f);
        return;
    }
    __shared__ float sW[32];
    if (threadIdx.x < 32) sW[threadIdx.x] = W2[threadIdx.x];
    __syncthreads();
    int n = bx * 256 + threadIdx.x;
    if (n >= NA) return;
    int cn = cnt[n];
    float dv = rsqrtf((float)cn + 1.0f);
    const int* row = csr + rowptr[n];
    float4 acc = dt2[n];
    int e = 0;
    for (; e + 3 < cn; e += 4) {
        int i0 = row[e], i1 = row[e + 1], i2 = row[e + 2], i3 = row[e + 3];
        float4 v0 = dt2[i0], v1 = dt2[i1], v2 = dt2[i2], v3 = dt2[i3];
        acc.x += (v0.x + v1.x) + (v2.x + v3.x);
        acc.y += (v0.y + v1.y) + (v2.y + v3.y);
        acc.z += (v0.z + v1.z) + (v2.z + v3.z);
        acc.w += (v0.w + v1.w) + (v2.w + v3.w);
    }
    for (; e < cn; e++) {
        float4 v = dt2[row[e]];
        acc.x += v.x; acc.y += v.y; acc.z += v.z; acc.w += v.w;
    }
    float a[4] = {acc.x, acc.y, acc.z, acc.w};
    float o[8];
#pragma unroll
    for (int f = 0; f < 8; f++) {
        float s = 0.f;
#pragma unroll
        for (int k = 0; k < 4; k++) s = fmaf(a[k], sW[k * 8 + f], s);
        o[f] = dv * fmaxf(fmaf(dv, s, b2[f]), 0.f);   // dt3 = dv*relu(...)
    }
    dt3[n] = make_uint4(f2h(o[0], o[1]), f2h(o[2], o[3]),
                        f2h(o[4], o[5]), f2h(o[6], o[7]));
}

// -------- K_E: gather3(fp16)+W3+segmax (782) -------------------------------
__global__ __launch_bounds__(256) void k_E(
        const uint4* __restrict__ dt3, const int* __restrict__ rowptr,
        const int* __restrict__ cnt, const int* __restrict__ csr,
        const float* __restrict__ W3, const float* __restrict__ b3,
        const int* __restrict__ batch, unsigned* __restrict__ g) {
    __shared__ float sW[128];
    __shared__ unsigned sg[32];
    __shared__ int sbmin;
    int id = blockIdx.x;                 // 256 nodes per block
    if (threadIdx.x < 128) sW[threadIdx.x] = W3[threadIdx.x];
    if (threadIdx.x < 32) sg[threadIdx.x] = 0u;
    if (threadIdx.x == 0) sbmin = batch[id * 256];
    __syncthreads();
    int n = id * 256 + threadIdx.x;
    if (n < NA) {
        int cn = cnt[n];
        float dv = rsqrtf((float)cn + 1.0f);
        const int* row = csr + rowptr[n];
        uint4 sv = dt3[n];
        float4 lo = h4f(sv.x, sv.y), hi = h4f(sv.z, sv.w);
        float a0 = lo.x, a1 = lo.y, a2 = lo.z, a3 = lo.w;
        float a4 = hi.x, a5 = hi.y, a6 = hi.z, a7 = hi.w;
        int e = 0;
        for (; e + 3 < cn; e += 4) {
            uint4 p0 = dt3[row[e]],     p1 = dt3[row[e + 1]];
            uint4 p2 = dt3[row[e + 2]], p3 = dt3[row[e + 3]];
            float4 l0 = h4f(p0.x, p0.y), h0 = h4f(p0.z, p0.w);
            float4 l1 = h4f(p1.x, p1.y), h1 = h4f(p1.z, p1.w);
            float4 l2 = h4f(p2.x, p2.y), h2 = h4f(p2.z, p2.w);
            float4 l3 = h4f(p3.x, p3.y), h3v = h4f(p3.z, p3.w);
            a0 += (l0.x + l1.x) + (l2.x + l3.x);
            a1 += (l0.y + l1.y) + (l2.y + l3.y);
            a2 += (l0.z + l1.z) + (l2.z + l3.z);
            a3 += (l0.w + l1.w) + (l2.w + l3.w);
            a4 += (h0.x + h1.x) + (h2.x + h3v.x);
            a5 += (h0.y + h1.y) + (h2.y + h3v.y);
            a6 += (h0.z + h1.z) + (h2.z + h3v.z);
            a7 += (h0.w + h1.w) + (h2.w + h3v.w);
        }
        for (; e < cn; e++) {
            uint4 p = dt3[row[e]];
            float4 l = h4f(p.x, p.y), h = h4f(p.z, p.w);
            a0 += l.x; a1 += l.y; a2 += l.z; a3 += l.w;
            a4 += h.x; a5 += h.y; a6 += h.z; a7 += h.w;
        }
        float af[8] = {a0, a1, a2, a3, a4, a5, a6, a7};
        int rb = batch[n] - sbmin;
        if (rb > 1) rb = 1;
#pragma unroll
        for (int f = 0; f < 16; f++) {
            float s = 0.f;
#pragma unroll
            for (int k = 0; k < 8; k++) s = fmaf(af[k], sW[k * 16 + f], s);
            float r = fmaxf(fmaf(dv, s, b3[f]), 0.f);
            atomicMax(&sg[rb * 16 + f], __float_as_uint(r));
        }
    }
    __syncthreads();
    if (threadIdx.x < 32) {
        unsigned v = sg[threadIdx.x];
        int rb2 = threadIdx.x >> 4, f = threadIdx.x & 15;
        int bbn = sbmin + rb2;
        if (v != 0u && bbn < NB) atomicMax(&g[bbn * 16 + f], v);
    }
}

// -------- headA: g -> relu(@Wg1) -> @Wg2 -> gvec; gp1 lives in LDS ---------
__global__ __launch_bounds__(256) void k_headA(
        const float* __restrict__ g, const float* __restrict__ Wg1,
        const float* __restrict__ bg1, const float* __restrict__ Wg2,
        const float* __restrict__ bg2, float* __restrict__ gvec) {
    __shared__ float sg[8 * 16];
    __shared__ float sgp1[8 * 1024];    // 32 KB
    int b0 = blockIdx.x * 8;
    if (threadIdx.x < 128) sg[threadIdx.x] = g[b0 * 16 + threadIdx.x];
    __syncthreads();
#pragma unroll
    for (int p = 0; p < 4; p++) {
        int j = threadIdx.x + 256 * p;
        float bj = bg1[j];
        float acc[8];
#pragma unroll
        for (int gg = 0; gg < 8; gg++) acc[gg] = bj;
#pragma unroll
        for (int k = 0; k < 16; k++) {
            float w = Wg1[(size_t)k * 1024 + j];
#pragma unroll
            for (int gg = 0; gg < 8; gg++) acc[gg] = fmaf(sg[gg * 16 + k], w, acc[gg]);
        }
#pragma unroll
        for (int gg = 0; gg < 8; gg++) sgp1[gg * 1024 + j] = fmaxf(acc[gg], 0.f);
    }
    __syncthreads();
    int j = threadIdx.x & 127;
    int gb = (threadIdx.x >> 7) * 4;    // 0 or 4
    float bj = bg2[j];
    float acc[4];
#pragma unroll
    for (int i = 0; i < 4; i++) acc[i] = bj;
#pragma unroll 4
    for (int k = 0; k < 1024; k++) {
        float w = Wg2[(size_t)k * 128 + j];
#pragma unroll
        for (int i = 0; i < 4; i++) acc[i] = fmaf(sgp1[(gb + i) * 1024 + k], w, acc[i]);
    }
#pragma unroll
    for (int i = 0; i < 4; i++)
        gvec[(size_t)(b0 + gb + i) * 128 + j] = acc[i];   // no relu (per reference)
}

// -------- headB: [gvec|cx] -> relu(@Wf1) -> relu(@Wf2) -> @Wo -> out -------
__global__ __launch_bounds__(256) void k_headB(
        const float* __restrict__ gvec, const float* __restrict__ cx,
        const float* __restrict__ Wf1, const float* __restrict__ bf1,
        const float* __restrict__ Wf2, const float* __restrict__ bf2,
        const float* __restrict__ Wo, const float* __restrict__ bo,
        float* __restrict__ out) {
    __shared__ float sxc[8 * 256];      // 8 KB
    __shared__ float sxf1[8 * 1024];    // 32 KB
    __shared__ float sxf2[8 * 512];     // 16 KB
    __shared__ float sred[256];
    int b0 = blockIdx.x * 8;
    for (int t = threadIdx.x; t < 8 * 256; t += 256) {
        int gg = t >> 8, k = t & 255;
        sxc[t] = (k < 128) ? gvec[(size_t)(b0 + gg) * 128 + k]
                           : cx[(size_t)(b0 + gg) * 128 + (k - 128)];
    }
    __syncthreads();
#pragma unroll
    for (int p = 0; p < 4; p++) {
        int j = threadIdx.x + 256 * p;
        float bj = bf1[j];
        float acc[8];
#pragma unroll
        for (int gg = 0; gg < 8; gg++) acc[gg] = bj;
#pragma unroll 4
        for (int k = 0; k < 256; k++) {
            float w = Wf1[(size_t)k * 1024 + j];
#pragma unroll
            for (int gg = 0; gg < 8; gg++) acc[gg] = fmaf(sxc[gg * 256 + k], w, acc[gg]);
        }
#pragma unroll
        for (int gg = 0; gg < 8; gg++) sxf1[gg * 1024 + j] = fmaxf(acc[gg], 0.f);
    }
    __syncthreads();
#pragma unroll
    for (int p = 0; p < 2; p++) {
        int j = threadIdx.x + 256 * p;
        float bj = bf2[j];
        float acc[8];
#pragma unroll
        for (int gg = 0; gg < 8; gg++) acc[gg] = bj;
#pragma unroll 4
        for (int k = 0; k < 1024; k++) {
            float w = Wf2[(size_t)k * 512 + j];
#pragma unroll
            for (int gg = 0; gg < 8; gg++) acc[gg] = fmaf(sxf1[gg * 1024 + k], w, acc[gg]);
        }
#pragma unroll
        for (int gg = 0; gg < 8; gg++) sxf2[gg * 512 + j] = fmaxf(acc[gg], 0.f);
    }
    __syncthreads();
    // out: 16 results (8 gg x 2 j); 16 lanes each sum a k-stripe, LDS reduce
    int gg = threadIdx.x >> 5;
    int jj = (threadIdx.x >> 4) & 1;
    int kl = threadIdx.x & 15;
    float part = 0.f;
#pragma unroll 4
    for (int i = 0; i < 32; i++) {
        int k = kl + 16 * i;
        part = fmaf(sxf2[gg * 512 + k], Wo[k * 2 + jj], part);
    }
    sred[threadIdx.x] = part;
    __syncthreads();
    if (kl < 8) sred[threadIdx.x] += sred[threadIdx.x + 8];
    __syncthreads();
    if (kl < 4) sred[threadIdx.x] += sred[threadIdx.x + 4];
    __syncthreads();
    if (kl < 2) sred[threadIdx.x] += sred[threadIdx.x + 2];
    __syncthreads();
    if (kl == 0) {
        float v = sred[threadIdx.x] + sred[threadIdx.x + 1] + bo[jj];
        out[(size_t)(b0 + gg) * 2 + jj] = v;
    }
}

extern "C" void kernel_launch(void* const* d_in, const int* in_sizes, int n_in,
                              void* d_out, int out_size, void* d_ws, size_t ws_size,
                              hipStream_t stream) {
    (void)in_sizes; (void)n_in; (void)out_size; (void)ws_size;
    const float* x   = (const float*)d_in[0];
    const int*  ei   = (const int*)d_in[1];
    const int*  batch= (const int*)d_in[2];
    const float* tgt = (const float*)d_in[3];
    const float* W1  = (const float*)d_in[4];  const float* b1  = (const float*)d_in[5];
    const float* W2  = (const float*)d_in[6];  const float* b2  = (const float*)d_in[7];
    const float* W3  = (const float*)d_in[8];  const float* b3  = (const float*)d_in[9];
    const float* Wg1 = (const float*)d_in[10]; const float* bg1 = (const float*)d_in[11];
    const float* Wg2 = (const float*)d_in[12]; const float* bg2 = (const float*)d_in[13];
    const float* K1  = (const float*)d_in[14]; const float* cb1 = (const float*)d_in[15];
    const float* K2  = (const float*)d_in[16]; const float* cb2 = (const float*)d_in[17];
    const float* K3  = (const float*)d_in[18]; const float* cb3 = (const float*)d_in[19];
    const float* Wxt = (const float*)d_in[20]; const float* bxt = (const float*)d_in[21];
    const float* Wf1 = (const float*)d_in[22]; const float* bf1 = (const float*)d_in[23];
    const float* Wf2 = (const float*)d_in[24]; const float* bf2 = (const float*)d_in[25];
    const float* Wo  = (const float*)d_in[26]; const float* bo  = (const float*)d_in[27];
    const int* srcp = ei;        // edge_index[0]
    const int* dstp = ei + NE;   // edge_index[1]

    float* ws = (float*)d_ws;
    float4* dt1 = (float4*)ws; ws += (size_t)NA * 4;   // dis*x          (3.2 MB)
    float4* dt2 = (float4*)ws; ws += (size_t)NA * 4;   // dis*out1       (3.2 MB)
    uint4*  dt3 = (uint4*)ws;  ws += (size_t)NA * 4;   // dis*out2 fp16  (3.2 MB)
    float* g     = ws; ws += NB * 16;
    float* gvec  = ws; ws += NB * 128;
    float* cx    = ws; ws += NB * 128;
    float* pool1 = ws; ws += (size_t)NB * 32 * 331;   // 5.42M
    float* pool2 = ws; ws += (size_t)NB * 64 * 108;   // 3.54M
    float* pool3 = ws; ws += (size_t)NB * 128 * 33;   // 2.16M
    int*   cnt    = (int*)ws; ws += NA;
    int*   rowptr = (int*)ws; ws += NA;
    int*   csr    = (int*)ws; ws += NE;               // compact CSR (12.8 MB)
    int*   gcursor= (int*)ws; ws += NBKT;
    unsigned* stage = (unsigned*)ws; ws += (size_t)NBKT * BKTCAP; // 16.8 MB, OWN region
    // (stage no longer aliases pools: conv2 writes pool2 concurrently with
    //  pass2 reading stage inside K_B)

    dim3 blk(256);

    k_init<<<32, blk, 0, stream>>>((unsigned*)g, gcursor);
    // K_A: pass1 (1000) || conv1 (1024)
    k_A<<<2024, blk, 0, stream>>>(srcp, dstp, gcursor, stage, tgt, K1, cb1, pool1);
    // K_B: pass2 (256) || conv2 tiled (1536)
    k_B<<<256 + 1536, blk, 0, stream>>>(stage, gcursor, rowptr, cnt, csr, x, dt1,
                                        pool1, K2, cb2, pool2);
    // K_C: gather1+W1 (782) || conv3 tiled (1024)
    k_C<<<782 + 1024, blk, 0, stream>>>(pool2, K3, cb3, pool3,
                                        dt1, rowptr, cnt, csr, W1, b1, dt2);
    // K_D: gather2+W2 (782) || mean+Wxt (64)
    k_D<<<782 + 64, blk, 0, stream>>>(dt2, rowptr, cnt, csr, W2, b2, dt3,
                                      pool3, Wxt, bxt, cx);
    // K_E: gather3+W3+segmax (782)
    k_E<<<782, blk, 0, stream>>>(dt3, rowptr, cnt, csr, W3, b3,
                                 batch, (unsigned*)g);

    // fused dense head (2 launches, intermediates in LDS)
    k_headA<<<64, blk, 0, stream>>>(g, Wg1, bg1, Wg2, bg2, gvec);
    k_headB<<<64, blk, 0, stream>>>(gvec, cx, Wf1, bf1, Wf2, bf2, Wo, bo,
                                    (float*)d_out);
}

// Round 12
// 668.710 us; speedup vs baseline: 1.2629x; 1.2629x over previous
//
#include <hip/hip_runtime.h>
#include <hip/hip_fp16.h>
#include <cstddef>

#define NA 200000
#define NE 3200000
#define NB 512
#define NBKT 256          // dst-range buckets
#define BKTN 782          // nodes per bucket
#define BKTCAP 16384      // stage capacity per bucket (exp 12500, sigma ~111)
#define NEPB 3200         // edges per pass-1 block (1000*3200 = NE)

// ---------------- fp16 helpers ----------------
union UH2 { unsigned u; __half2 h; };
__device__ __forceinline__ float4 h4f(unsigned a, unsigned b) {
    UH2 x, y; x.u = a; y.u = b;
    float2 fa = __half22float2(x.h), fb = __half22float2(y.h);
    return make_float4(fa.x, fa.y, fb.x, fb.y);
}
__device__ __forceinline__ unsigned f2h(float a, float b) {
    UH2 r; r.h = __float22half2_rn(make_float2(a, b));
    return r.u;
}

// -------- init: g=0, gcursor, gvec<-bg2, xf2<-bf2 (atomic accumulators) ----
__global__ void k_init(unsigned* g, int* gcursor,
                       float* gvec, const float* __restrict__ bg2,
                       float* xf2, const float* __restrict__ bf2) {
    int i = blockIdx.x * blockDim.x + threadIdx.x;
    if (i < NB * 16) g[i] = 0u;
    if (i < NBKT) gcursor[i] = i * BKTCAP;
    if (i < NB * 128) gvec[i] = bg2[i & 127];
    if (i < NB * 512) xf2[i] = bf2[i & 511];
}

// ---- pass 1: bin edges into 256 dst-range buckets (LDS hist), payload
// (dstLocal<<18 | src), src<2^18; int4-vectorized edge reads ----
__global__ __launch_bounds__(256) void k_pass1(
        const int* __restrict__ src, const int* __restrict__ dst,
        int* __restrict__ gcursor, unsigned* __restrict__ stage) {
    __shared__ int hcnt[NBKT];
    __shared__ int hbase[NBKT];
    int e0 = blockIdx.x * NEPB;
    hcnt[threadIdx.x] = 0;
    __syncthreads();
    const int4* d4 = (const int4*)(dst + e0);
    for (int i = threadIdx.x; i < NEPB / 4; i += 256) {
        int4 d = d4[i];
        atomicAdd(&hcnt[d.x / BKTN], 1);
        atomicAdd(&hcnt[d.y / BKTN], 1);
        atomicAdd(&hcnt[d.z / BKTN], 1);
        atomicAdd(&hcnt[d.w / BKTN], 1);
    }
    __syncthreads();
    hbase[threadIdx.x] = atomicAdd(&gcursor[threadIdx.x], hcnt[threadIdx.x]);
    hcnt[threadIdx.x] = 0;
    __syncthreads();
    const int4* s4 = (const int4*)(src + e0);
    for (int i = threadIdx.x; i < NEPB / 4; i += 256) {
        int4 d = d4[i];
        int4 s = s4[i];
        int ds[4] = {d.x, d.y, d.z, d.w};
        int ss[4] = {s.x, s.y, s.z, s.w};
#pragma unroll
        for (int j = 0; j < 4; j++) {
            int bkt = ds[j] / BKTN;
            int dloc = ds[j] - bkt * BKTN;
            int k = atomicAdd(&hcnt[bkt], 1);
            stage[hbase[bkt] + k] = ((unsigned)dloc << 18) | (unsigned)ss[j];
        }
    }
}

// ---- pass 2: per-bucket count + scan + scatter into compact CSR;
// bucket base inline; also emits dt1 = dis * x (fp32) ----
__global__ __launch_bounds__(256) void k_pass2(
        const unsigned* __restrict__ stage, const int* __restrict__ gcursor,
        int* __restrict__ rowptr, int* __restrict__ cnt, int* __restrict__ csr,
        const float* __restrict__ x, float4* __restrict__ dt1) {
    __shared__ int lcnt[BKTN];
    __shared__ int lpos[BKTN];
    __shared__ int partial[256];
    __shared__ int sbase;
    int t = threadIdx.x;
    int bkt = blockIdx.x;
    int tot = gcursor[t] - t * BKTCAP;
    partial[t] = tot;
    __syncthreads();
#pragma unroll
    for (int off = 1; off < 256; off <<= 1) {
        int u = (t >= off) ? partial[t - off] : 0;
        __syncthreads();
        partial[t] += u;
        __syncthreads();
    }
    if (t == 0) sbase = (bkt == 0) ? 0 : partial[bkt - 1];
    __syncthreads();
    int base = sbase;
    int n0 = bkt * BKTN;
    int ncnt = (NA - n0 < BKTN) ? (NA - n0) : BKTN;
    int eBeg = bkt * BKTCAP;
    int eCnt = gcursor[bkt] - eBeg;
    for (int i = t; i < BKTN; i += 256) lcnt[i] = 0;
    __syncthreads();
    for (int i = t; i < eCnt; i += 256)
        atomicAdd(&lcnt[stage[eBeg + i] >> 18], 1);
    __syncthreads();
    int mysum = 0;
#pragma unroll
    for (int j = 0; j < 4; j++) {
        int node = 4 * t + j;
        if (node < ncnt) mysum += lcnt[node];
    }
    partial[t] = mysum;
    __syncthreads();
#pragma unroll
    for (int off = 1; off < 256; off <<= 1) {
        int u = (t >= off) ? partial[t - off] : 0;
        __syncthreads();
        partial[t] += u;
        __syncthreads();
    }
    int running = partial[t] - mysum;
#pragma unroll
    for (int j = 0; j < 4; j++) {
        int node = 4 * t + j;
        if (node < ncnt) {
            lpos[node] = running;
            rowptr[n0 + node] = base + running;
            cnt[n0 + node] = lcnt[node];
            running += lcnt[node];
        }
    }
    __syncthreads();
    for (int i = t; i < eCnt; i += 256) {
        unsigned v = stage[eBeg + i];
        int dloc = v >> 18;
        int s = v & 0x3FFFF;
        int k = atomicAdd(&lpos[dloc], 1);
        csr[base + k] = s;
    }
    for (int i = t; i < ncnt; i += 256) {
        int n = n0 + i;
        float4 p = ((const float4*)x)[n];
        float dv = rsqrtf((float)lcnt[i] + 1.0f);
        dt1[n] = make_float4(dv * p.x, dv * p.y, dv * p.z, dv * p.w);
    }
}

// ---------------- conv1 device body (untiled, transpose load) --------------
template<int CIN, int COUT, int OBLK, int LIN, int PITCH, int POUT, int NTT>
__device__ __forceinline__ void dev_conv1(int b, int oy,
        const float* __restrict__ in, const float* __restrict__ Kw,
        const float* __restrict__ bias, float* __restrict__ out) {
    constexpr int SPO = 256 / OBLK;
    constexpr int PT = (NTT < 4) ? NTT : 4;
    constexpr int NPASS = (NTT + PT - 1) / PT;
    __shared__ __align__(16) float s_in[CIN * PITCH];
    for (int idx = threadIdx.x; idx < CIN * PITCH; idx += 256) s_in[idx] = 0.f;
    __syncthreads();
    for (int idx = threadIdx.x; idx < LIN * CIN; idx += 256) {
        int p = idx / CIN, c = idx - p * CIN;
        s_in[c * PITCH + p] = in[(size_t)b * (LIN * CIN) + idx];
    }
    __syncthreads();
    int ol = threadIdx.x / SPO;
    int s  = threadIdx.x - ol * SPO;
    int o  = oy * OBLK + ol;
    float bo = bias[o];
    const float* wrow = Kw + (size_t)o * CIN * 8;
    for (int pass = 0; pass < NPASS; pass++) {
        float acc[PT][12];
#pragma unroll
        for (int tt = 0; tt < PT; tt++)
#pragma unroll
            for (int j = 0; j < 12; j++) acc[tt][j] = 0.f;
        bool vld[PT]; int tgs[PT];
#pragma unroll
        for (int tt = 0; tt < PT; tt++) {
            int ta = pass * PT + tt;
            int tg = s + SPO * ta;
            tgs[tt] = tg;
            vld[tt] = (ta < NTT) && (4 * tg < POUT);
        }
        for (int i = 0; i < CIN; i++) {
            float wa[8];
            const float4* wp = (const float4*)(wrow + (size_t)i * 8);
            *(float4*)&wa[0] = wp[0];
            *(float4*)&wa[4] = wp[1];
#pragma unroll
            for (int tt = 0; tt < PT; tt++) {
                if (vld[tt]) {
                    const float4* xr = (const float4*)&s_in[i * PITCH + 12 * tgs[tt]];
                    float xa[20];
#pragma unroll
                    for (int q = 0; q < 5; q++) *(float4*)&xa[4 * q] = xr[q];
#pragma unroll
                    for (int j = 0; j < 12; j++) {
                        float sm = acc[tt][j];
#pragma unroll
                        for (int k = 0; k < 8; k++) sm = fmaf(xa[j + k], wa[k], sm);
                        acc[tt][j] = sm;
                    }
                }
            }
        }
#pragma unroll
        for (int tt = 0; tt < PT; tt++) {
            if (vld[tt]) {
#pragma unroll
                for (int p = 0; p < 4; p++) {
                    int P = 4 * tgs[tt] + p;
                    if (P < POUT) {
                        float m = fmaxf(fmaxf(acc[tt][3 * p], acc[tt][3 * p + 1]), acc[tt][3 * p + 2]);
                        out[((size_t)b * COUT + o) * POUT + P] = fmaxf(m + bo, 0.f);
                    }
                }
            }
        }
    }
}

// ------------- tiled conv device body (seq-axis tiles, small LDS) ----------
template<int CIN, int COUT, int OBLK, int LIN, int PITCH, int TPOOL, int POUT>
__device__ __forceinline__ void dev_conv_t(int b, int oy, int tile,
        const float* __restrict__ in, const float* __restrict__ Kw,
        const float* __restrict__ bias, float* __restrict__ out) {
    constexpr int SPO = 256 / OBLK;
    constexpr int NQ = TPOOL / 4;
    constexpr int NTT = (NQ + SPO - 1) / SPO;
    constexpr int SPAN = 3 * TPOOL + 7;
    __shared__ __align__(16) float s_in[CIN * PITCH];
    int p0 = tile * TPOOL;
    int cbase = 3 * p0;
    for (int idx = threadIdx.x; idx < CIN * PITCH; idx += 256) {
        int c = idx / PITCH, p = idx - c * PITCH;
        int gp = cbase + p;
        float v = 0.f;
        if (p < SPAN && gp < LIN) v = in[((size_t)b * CIN + c) * LIN + gp];
        s_in[idx] = v;
    }
    __syncthreads();
    int ol = threadIdx.x / SPO;
    int s  = threadIdx.x - ol * SPO;
    int o  = oy * OBLK + ol;
    float bo = bias[o];
    const float* wrow = Kw + (size_t)o * CIN * 8;
    float acc[NTT][12];
#pragma unroll
    for (int tt = 0; tt < NTT; tt++)
#pragma unroll
        for (int j = 0; j < 12; j++) acc[tt][j] = 0.f;
    bool vld[NTT]; int qgs[NTT];
#pragma unroll
    for (int tt = 0; tt < NTT; tt++) {
        int qg = s + SPO * tt;
        qgs[tt] = qg;
        vld[tt] = (qg < NQ) && (p0 + 4 * qg < POUT);
    }
    for (int i = 0; i < CIN; i++) {
        float wa[8];
        const float4* wp = (const float4*)(wrow + (size_t)i * 8);
        *(float4*)&wa[0] = wp[0];
        *(float4*)&wa[4] = wp[1];
#pragma unroll
        for (int tt = 0; tt < NTT; tt++) {
            if (vld[tt]) {
                const float4* xr = (const float4*)&s_in[i * PITCH + 12 * qgs[tt]];
                float xa[20];
#pragma unroll
                for (int q = 0; q < 5; q++) *(float4*)&xa[4 * q] = xr[q];
#pragma unroll
                for (int j = 0; j < 12; j++) {
                    float sm = acc[tt][j];
#pragma unroll
                    for (int k = 0; k < 8; k++) sm = fmaf(xa[j + k], wa[k], sm);
                    acc[tt][j] = sm;
                }
            }
        }
    }
#pragma unroll
    for (int tt = 0; tt < NTT; tt++) {
        if (vld[tt]) {
#pragma unroll
            for (int p = 0; p < 4; p++) {
                int P = p0 + 4 * qgs[tt] + p;
                if (P < POUT) {
                    float m = fmaxf(fmaxf(acc[tt][3 * p], acc[tt][3 * p + 1]), acc[tt][3 * p + 2]);
                    out[((size_t)b * COUT + o) * POUT + P] = fmaxf(m + bo, 0.f);
                }
            }
        }
    }
}

// -------- K_B: conv1 (1024) || gather1 over dt1 + W1 epilogue (782) --------
__global__ __launch_bounds__(256) void k_fused_B(
        const float* __restrict__ tgt, const float* __restrict__ K1,
        const float* __restrict__ cb1, float* __restrict__ pool1,
        const float4* __restrict__ dt1, const int* __restrict__ rowptr,
        const int* __restrict__ cnt, const int* __restrict__ csr,
        const float* __restrict__ W1, const float* __restrict__ b1,
        float4* __restrict__ dt2) {
    int bx = blockIdx.x;
    if (bx < 1024) {
        dev_conv1<5, 32, 16, 1000, 1008, 331, 6>(bx & 511, bx >> 9, tgt, K1, cb1, pool1);
        return;
    }
    __shared__ float sW[16];
    if (threadIdx.x < 16) sW[threadIdx.x] = W1[threadIdx.x];
    __syncthreads();
    int n = (bx - 1024) * 256 + threadIdx.x;
    if (n >= NA) return;
    int cn = cnt[n];
    float dv = rsqrtf((float)cn + 1.0f);
    const int* row = csr + rowptr[n];
    float4 acc = dt1[n];
    int e = 0;
    for (; e + 3 < cn; e += 4) {
        int i0 = row[e], i1 = row[e + 1], i2 = row[e + 2], i3 = row[e + 3];
        float4 v0 = dt1[i0], v1 = dt1[i1], v2 = dt1[i2], v3 = dt1[i3];
        acc.x += (v0.x + v1.x) + (v2.x + v3.x);
        acc.y += (v0.y + v1.y) + (v2.y + v3.y);
        acc.z += (v0.z + v1.z) + (v2.z + v3.z);
        acc.w += (v0.w + v1.w) + (v2.w + v3.w);
    }
    for (; e < cn; e++) {
        float4 v = dt1[row[e]];
        acc.x += v.x; acc.y += v.y; acc.z += v.z; acc.w += v.w;
    }
    const float4 bq = *(const float4*)b1;
    float a[4] = {acc.x, acc.y, acc.z, acc.w};
    float bb[4] = {bq.x, bq.y, bq.z, bq.w};
    float o[4];
#pragma unroll
    for (int f = 0; f < 4; f++) {
        float s = 0.f;
#pragma unroll
        for (int k = 0; k < 4; k++) s = fmaf(a[k], sW[k * 4 + f], s);
        o[f] = dv * fmaxf(fmaf(dv, s, bb[f]), 0.f);   // dt2 = dv*relu(...)
    }
    dt2[n] = make_float4(o[0], o[1], o[2], o[3]);
}

// -------- K_C: conv2 tiled (1536) || gather2 over dt2 + W2 epilogue (782) --
__global__ __launch_bounds__(256) void k_fused_C(
        const float* __restrict__ pool1, const float* __restrict__ K2,
        const float* __restrict__ cb2, float* __restrict__ pool2,
        const float4* __restrict__ dt2, const int* __restrict__ rowptr,
        const int* __restrict__ cnt, const int* __restrict__ csr,
        const float* __restrict__ W2, const float* __restrict__ b2,
        uint4* __restrict__ dt3) {
    int bx = blockIdx.x;
    if (bx < 1536) {
        dev_conv_t<32, 64, 64, 331, 116, 36, 108>(bx & 511, 0, bx >> 9, pool1, K2, cb2, pool2);
        return;
    }
    __shared__ float sW[32];
    if (threadIdx.x < 32) sW[threadIdx.x] = W2[threadIdx.x];
    __syncthreads();
    int n = (bx - 1536) * 256 + threadIdx.x;
    if (n >= NA) return;
    int cn = cnt[n];
    float dv = rsqrtf((float)cn + 1.0f);
    const int* row = csr + rowptr[n];
    float4 acc = dt2[n];
    int e = 0;
    for (; e + 3 < cn; e += 4) {
        int i0 = row[e], i1 = row[e + 1], i2 = row[e + 2], i3 = row[e + 3];
        float4 v0 = dt2[i0], v1 = dt2[i1], v2 = dt2[i2], v3 = dt2[i3];
        acc.x += (v0.x + v1.x) + (v2.x + v3.x);
        acc.y += (v0.y + v1.y) + (v2.y + v3.y);
        acc.z += (v0.z + v1.z) + (v2.z + v3.z);
        acc.w += (v0.w + v1.w) + (v2.w + v3.w);
    }
    for (; e < cn; e++) {
        float4 v = dt2[row[e]];
        acc.x += v.x; acc.y += v.y; acc.z += v.z; acc.w += v.w;
    }
    float a[4] = {acc.x, acc.y, acc.z, acc.w};
    float o[8];
#pragma unroll
    for (int f = 0; f < 8; f++) {
        float s = 0.f;
#pragma unroll
        for (int k = 0; k < 4; k++) s = fmaf(a[k], sW[k * 8 + f], s);
        o[f] = dv * fmaxf(fmaf(dv, s, b2[f]), 0.f);   // dt3 = dv*relu(...)
    }
    dt3[n] = make_uint4(f2h(o[0], o[1]), f2h(o[2], o[3]),
                        f2h(o[4], o[5]), f2h(o[6], o[7]));
}

// -------- K_D: conv3 tiled (1024) || gather3 (fp16 dt3, L2-resident)
//          + W3 epilogue + segmax (782) ------------------------------------
__global__ __launch_bounds__(256) void k_fused_D(
        const float* __restrict__ pool2, const float* __restrict__ K3,
        const float* __restrict__ cb3, float* __restrict__ pool3,
        const uint4* __restrict__ dt3, const int* __restrict__ rowptr,
        const int* __restrict__ cnt, const int* __restrict__ csr,
        const float* __restrict__ W3, const float* __restrict__ b3,
        const int* __restrict__ batch, unsigned* __restrict__ g) {
    int bx = blockIdx.x;
    if (bx < 1024) {
        dev_conv_t<64, 128, 128, 108, 68, 20, 33>(bx & 511, 0, bx >> 9, pool2, K3, cb3, pool3);
        return;
    }
    __shared__ float sW[128];
    __shared__ unsigned sg[32];
    __shared__ int sbmin;
    int id = bx - 1024;                  // 0..781, 256 nodes per block
    if (threadIdx.x < 128) sW[threadIdx.x] = W3[threadIdx.x];
    if (threadIdx.x < 32) sg[threadIdx.x] = 0u;
    if (threadIdx.x == 0) sbmin = batch[id * 256];
    __syncthreads();
    int n = id * 256 + threadIdx.x;
    if (n < NA) {
        int cn = cnt[n];
        float dv = rsqrtf((float)cn + 1.0f);
        const int* row = csr + rowptr[n];
        uint4 sv = dt3[n];
        float4 lo = h4f(sv.x, sv.y), hi = h4f(sv.z, sv.w);
        float a0 = lo.x, a1 = lo.y, a2 = lo.z, a3 = lo.w;
        float a4 = hi.x, a5 = hi.y, a6 = hi.z, a7 = hi.w;
        int e = 0;
        for (; e + 3 < cn; e += 4) {
            uint4 p0 = dt3[row[e]],     p1 = dt3[row[e + 1]];
            uint4 p2 = dt3[row[e + 2]], p3 = dt3[row[e + 3]];
            float4 l0 = h4f(p0.x, p0.y), h0 = h4f(p0.z, p0.w);
            float4 l1 = h4f(p1.x, p1.y), h1 = h4f(p1.z, p1.w);
            float4 l2 = h4f(p2.x, p2.y), h2 = h4f(p2.z, p2.w);
            float4 l3 = h4f(p3.x, p3.y), h3v = h4f(p3.z, p3.w);
            a0 += (l0.x + l1.x) + (l2.x + l3.x);
            a1 += (l0.y + l1.y) + (l2.y + l3.y);
            a2 += (l0.z + l1.z) + (l2.z + l3.z);
            a3 += (l0.w + l1.w) + (l2.w + l3.w);
            a4 += (h0.x + h1.x) + (h2.x + h3v.x);
            a5 += (h0.y + h1.y) + (h2.y + h3v.y);
            a6 += (h0.z + h1.z) + (h2.z + h3v.z);
            a7 += (h0.w + h1.w) + (h2.w + h3v.w);
        }
        for (; e < cn; e++) {
            uint4 p = dt3[row[e]];
            float4 l = h4f(p.x, p.y), h = h4f(p.z, p.w);
            a0 += l.x; a1 += l.y; a2 += l.z; a3 += l.w;
            a4 += h.x; a5 += h.y; a6 += h.z; a7 += h.w;
        }
        float af[8] = {a0, a1, a2, a3, a4, a5, a6, a7};
        int rb = batch[n] - sbmin;
        if (rb > 1) rb = 1;
#pragma unroll
        for (int f = 0; f < 16; f++) {
            float s = 0.f;
#pragma unroll
            for (int k = 0; k < 8; k++) s = fmaf(af[k], sW[k * 16 + f], s);
            float r = fmaxf(fmaf(dv, s, b3[f]), 0.f);
            atomicMax(&sg[rb * 16 + f], __float_as_uint(r));
        }
    }
    __syncthreads();
    if (threadIdx.x < 32) {
        unsigned v = sg[threadIdx.x];
        int rb2 = threadIdx.x >> 4, f = threadIdx.x & 15;
        int bbn = sbmin + rb2;
        if (v != 0u && bbn < NB) atomicMax(&g[bbn * 16 + f], v);
    }
}

// -------- head1: (g@Wg1 -> gp1, 256 blk) || (mean->@Wxt -> cx, 64 blk) -----
__global__ __launch_bounds__(256) void k_head1(
        const float* __restrict__ g, const float* __restrict__ Wg1,
        const float* __restrict__ bg1, float* __restrict__ gp1,
        const float* __restrict__ pool3, const float* __restrict__ Wxt,
        const float* __restrict__ bxt, float* __restrict__ cx) {
    int bx = blockIdx.x;
    if (bx < 256) {
        __shared__ float sa[8 * 16];
        int b0 = (bx >> 2) * 8;
        if (threadIdx.x < 128)
            sa[threadIdx.x] = g[b0 * 16 + threadIdx.x];
        __syncthreads();
        int j = (bx & 3) * 256 + threadIdx.x;
        float bj = bg1[j];
        float acc[8];
#pragma unroll
        for (int gg = 0; gg < 8; gg++) acc[gg] = bj;
#pragma unroll
        for (int k = 0; k < 16; k++) {
            float w = Wg1[(size_t)k * 1024 + j];
#pragma unroll
            for (int gg = 0; gg < 8; gg++) acc[gg] = fmaf(sa[gg * 16 + k], w, acc[gg]);
        }
#pragma unroll
        for (int gg = 0; gg < 8; gg++)
            gp1[(size_t)(b0 + gg) * 1024 + j] = fmaxf(acc[gg], 0.f);
    } else {
        __shared__ float sa[8 * 128];
        int b0 = (bx - 256) * 8;
        for (int t = threadIdx.x; t < 8 * 128; t += 256) {
            int gg = t >> 7, k = t & 127;
            const float* r = pool3 + ((size_t)(b0 + gg) * 128 + k) * 33;
            float s = 0.f;
#pragma unroll
            for (int p = 0; p < 33; p++) s += r[p];
            sa[t] = s * (1.f / 33.f);
        }
        __syncthreads();
        int j = threadIdx.x;
        if (j >= 128) return;
        float bj = bxt[j];
        float acc[8];
#pragma unroll
        for (int gg = 0; gg < 8; gg++) acc[gg] = bj;
#pragma unroll 4
        for (int k = 0; k < 128; k++) {
            float w = Wxt[(size_t)k * 128 + j];
#pragma unroll
            for (int gg = 0; gg < 8; gg++) acc[gg] = fmaf(sa[gg * 128 + k], w, acc[gg]);
        }
#pragma unroll
        for (int gg = 0; gg < 8; gg++)
            cx[(size_t)(b0 + gg) * 128 + j] = fmaxf(acc[gg], 0.f);
    }
}

// -------- gvec += (gp1 K-slice)@Wg2 ; K-split x4, fp32 atomicAdd -----------
__global__ __launch_bounds__(256) void k_gvec_ks(
        const float* __restrict__ gp1, const float* __restrict__ Wg2,
        float* __restrict__ gvec) {
    __shared__ float sa[8 * 256];       // 8 KB
    int k0 = blockIdx.x * 256;          // K-split 0..3
    int b0 = blockIdx.y * 8;
    for (int t = threadIdx.x; t < 8 * 256; t += 256) {
        int gg = t >> 8, k = t & 255;
        sa[t] = gp1[(size_t)(b0 + gg) * 1024 + k0 + k];
    }
    __syncthreads();
    int j = threadIdx.x;
    if (j >= 128) return;
    float acc[8];
#pragma unroll
    for (int gg = 0; gg < 8; gg++) acc[gg] = 0.f;
#pragma unroll 4
    for (int k = 0; k < 256; k++) {
        float w = Wg2[(size_t)(k0 + k) * 128 + j];
#pragma unroll
        for (int gg = 0; gg < 8; gg++) acc[gg] = fmaf(sa[gg * 256 + k], w, acc[gg]);
    }
#pragma unroll
    for (int gg = 0; gg < 8; gg++)
        atomicAdd(&gvec[(size_t)(b0 + gg) * 128 + j], acc[gg]);
}

// -------- dense with concatenated input [gvec | cx] -> relu -> xf1 ---------
template<int KA, int KB2, int BGRP, bool RELU>
__global__ __launch_bounds__(256) void k_dense_cat_g(
        const float* __restrict__ A1, const float* __restrict__ A2,
        const float* __restrict__ W, const float* __restrict__ bias,
        float* __restrict__ out, int ncols) {
    constexpr int K = KA + KB2;
    __shared__ float sa[BGRP * K];
    int b0 = blockIdx.y * BGRP;
    for (int t = threadIdx.x; t < BGRP * K; t += 256) {
        int gg = t / K, k = t - gg * K;
        sa[t] = (k < KA) ? A1[(size_t)(b0 + gg) * KA + k]
                         : A2[(size_t)(b0 + gg) * KB2 + (k - KA)];
    }
    __syncthreads();
    int j = blockIdx.x * 256 + threadIdx.x;
    if (j >= ncols) return;
    float bj = bias[j];
    float acc[BGRP];
#pragma unroll
    for (int gg = 0; gg < BGRP; gg++) acc[gg] = bj;
#pragma unroll 4
    for (int k = 0; k < K; k++) {
        float w = W[(size_t)k * ncols + j];
#pragma unroll
        for (int gg = 0; gg < BGRP; gg++) acc[gg] = fmaf(sa[gg * K + k], w, acc[gg]);
    }
#pragma unroll
    for (int gg = 0; gg < BGRP; gg++) {
        float v = acc[gg];
        if (RELU) v = fmaxf(v, 0.f);
        out[(size_t)(b0 + gg) * ncols + j] = v;
    }
}

// -------- xf2 += (xf1 K-slice)@Wf2 ; K-split x2, j-split x2 ----------------
// relu deferred to k_dense_out read
__global__ __launch_bounds__(256) void k_xf2_ks(
        const float* __restrict__ xf1, const float* __restrict__ Wf2,
        float* __restrict__ xf2) {
    __shared__ float sa[8 * 512];       // 16 KB
    int jb = blockIdx.x & 1;
    int k0 = (blockIdx.x >> 1) * 512;
    int b0 = blockIdx.y * 8;
    for (int t = threadIdx.x; t < 8 * 512; t += 256) {
        int gg = t >> 9, k = t & 511;
        sa[t] = xf1[(size_t)(b0 + gg) * 1024 + k0 + k];
    }
    __syncthreads();
    int j = jb * 256 + threadIdx.x;
    float acc[8];
#pragma unroll
    for (int gg = 0; gg < 8; gg++) acc[gg] = 0.f;
#pragma unroll 4
    for (int k = 0; k < 512; k++) {
        float w = Wf2[(size_t)(k0 + k) * 512 + j];
#pragma unroll
        for (int gg = 0; gg < 8; gg++) acc[gg] = fmaf(sa[gg * 512 + k], w, acc[gg]);
    }
#pragma unroll
    for (int gg = 0; gg < 8; gg++)
        atomicAdd(&xf2[(size_t)(b0 + gg) * 512 + j], acc[gg]);
}

// final 512->2 layer; applies the deferred relu on xf2
__global__ __launch_bounds__(256) void k_dense_out(
        const float* __restrict__ A, const float* __restrict__ W,
        const float* __restrict__ bias, float* __restrict__ out) {
    int idx = blockIdx.x * 256 + threadIdx.x;
    if (idx >= NB * 2) return;
    int b = idx >> 1, j = idx & 1;
    float s = bias[j];
#pragma unroll 8
    for (int k = 0; k < 512; k++)
        s = fmaf(fmaxf(A[b * 512 + k], 0.f), W[k * 2 + j], s);
    out[idx] = s;
}

extern "C" void kernel_launch(void* const* d_in, const int* in_sizes, int n_in,
                              void* d_out, int out_size, void* d_ws, size_t ws_size,
                              hipStream_t stream) {
    (void)in_sizes; (void)n_in; (void)out_size; (void)ws_size;
    const float* x   = (const float*)d_in[0];
    const int*  ei   = (const int*)d_in[1];
    const int*  batch= (const int*)d_in[2];
    const float* tgt = (const float*)d_in[3];
    const float* W1  = (const float*)d_in[4];  const float* b1  = (const float*)d_in[5];
    const float* W2  = (const float*)d_in[6];  const float* b2  = (const float*)d_in[7];
    const float* W3  = (const float*)d_in[8];  const float* b3  = (const float*)d_in[9];
    const float* Wg1 = (const float*)d_in[10]; const float* bg1 = (const float*)d_in[11];
    const float* Wg2 = (const float*)d_in[12]; const float* bg2 = (const float*)d_in[13];
    const float* K1  = (const float*)d_in[14]; const float* cb1 = (const float*)d_in[15];
    const float* K2  = (const float*)d_in[16]; const float* cb2 = (const float*)d_in[17];
    const float* K3  = (const float*)d_in[18]; const float* cb3 = (const float*)d_in[19];
    const float* Wxt = (const float*)d_in[20]; const float* bxt = (const float*)d_in[21];
    const float* Wf1 = (const float*)d_in[22]; const float* bf1 = (const float*)d_in[23];
    const float* Wf2 = (const float*)d_in[24]; const float* bf2 = (const float*)d_in[25];
    const float* Wo  = (const float*)d_in[26]; const float* bo  = (const float*)d_in[27];
    const int* srcp = ei;        // edge_index[0]
    const int* dstp = ei + NE;   // edge_index[1]

    float* ws = (float*)d_ws;
    float4* dt1 = (float4*)ws; ws += (size_t)NA * 4;   // dis*x          (3.2 MB)
    float4* dt2 = (float4*)ws; ws += (size_t)NA * 4;   // dis*out1       (3.2 MB)
    uint4*  dt3 = (uint4*)ws;  ws += (size_t)NA * 4;   // dis*out2 fp16  (3.2 MB)
    float* g     = ws; ws += NB * 16;
    float* gp1   = ws; ws += NB * 1024;
    float* gvec  = ws; ws += NB * 128;
    float* cx    = ws; ws += NB * 128;
    float* xf1   = ws; ws += NB * 1024;
    float* xf2   = ws; ws += NB * 512;
    float* pool1 = ws; ws += (size_t)NB * 32 * 331;   // 5.42M (stage aliases)
    float* pool2 = ws; ws += (size_t)NB * 64 * 108;   // 3.54M
    float* pool3 = ws; ws += (size_t)NB * 128 * 33;   // 2.16M
    int*   cnt    = (int*)ws; ws += NA;
    int*   rowptr = (int*)ws; ws += NA;
    int*   csr    = (int*)ws; ws += NE;               // compact CSR
    int*   gcursor= (int*)ws; ws += NBKT;

    // stage (4.19M u32) aliases pool1: alive pass1->pass2; pool1 first
    // written by conv1 inside K_B, strictly after pass2.
    unsigned* stage = (unsigned*)pool1;

    dim3 blk(256);

    k_init<<<1024, blk, 0, stream>>>((unsigned*)g, gcursor, gvec, bg2, xf2, bf2);
    k_pass1<<<1000, blk, 0, stream>>>(srcp, dstp, gcursor, stage);
    k_pass2<<<NBKT, blk, 0, stream>>>(stage, gcursor, rowptr, cnt, csr, x, dt1);

    // K_B: conv1 (1024) || gather1+W1 (782)
    k_fused_B<<<1806, blk, 0, stream>>>(tgt, K1, cb1, pool1,
                                        dt1, rowptr, cnt, csr, W1, b1, dt2);
    // K_C: conv2 tiled (1536) || gather2+W2 (782)
    k_fused_C<<<2318, blk, 0, stream>>>(pool1, K2, cb2, pool2,
                                        dt2, rowptr, cnt, csr, W2, b2, dt3);
    // K_D: conv3 tiled (1024) || gather3(fp16)+W3+segmax (782)
    k_fused_D<<<1806, blk, 0, stream>>>(pool2, K3, cb3, pool3,
                                        dt3, rowptr, cnt, csr, W3, b3,
                                        batch, (unsigned*)g);

    // dense head (parallelism-first: every kernel >=256 blocks)
    k_head1<<<320, blk, 0, stream>>>(g, Wg1, bg1, gp1, pool3, Wxt, bxt, cx);
    k_gvec_ks<<<dim3(4, 64), blk, 0, stream>>>(gp1, Wg2, gvec);
    k_dense_cat_g<128, 128, 8, true><<<dim3(4, 64), blk, 0, stream>>>(gvec, cx, Wf1, bf1, xf1, 1024);
    k_xf2_ks<<<dim3(4, 64), blk, 0, stream>>>(xf1, Wf2, xf2);
    k_dense_out<<<4, blk, 0, stream>>>(xf2, Wo, bo, (float*)d_out);
}

// Round 13
// 624.346 us; speedup vs baseline: 1.3527x; 1.0711x over previous
//
#include <hip/hip_runtime.h>
#include <hip/hip_fp16.h>
#include <cstddef>

#define NA 200000
#define NE 3200000
#define NB 512
#define NBKT 256          // dst-range buckets
#define BKTN 782          // nodes per bucket
#define BKTCAP 16384      // stage capacity per bucket (exp 12500, sigma ~111)
#define NEPB 3200         // edges per pass-1 block (1000*3200 = NE)

// ---------------- fp16 helpers ----------------
union UH2 { unsigned u; __half2 h; };
__device__ __forceinline__ float4 h4f(unsigned a, unsigned b) {
    UH2 x, y; x.u = a; y.u = b;
    float2 fa = __half22float2(x.h), fb = __half22float2(y.h);
    return make_float4(fa.x, fa.y, fb.x, fb.y);
}
__device__ __forceinline__ unsigned f2h(float a, float b) {
    UH2 r; r.h = __float22half2_rn(make_float2(a, b));
    return r.u;
}

// -------- init: g=0, gcursor, gvec<-bg2, xf2<-bf2 (atomic accumulators) ----
__global__ void k_init(unsigned* g, int* gcursor,
                       float* gvec, const float* __restrict__ bg2,
                       float* xf2, const float* __restrict__ bf2) {
    int i = blockIdx.x * blockDim.x + threadIdx.x;
    if (i < NB * 16) g[i] = 0u;
    if (i < NBKT) gcursor[i] = i * BKTCAP;
    if (i < NB * 128) gvec[i] = bg2[i & 127];
    if (i < NB * 512) xf2[i] = bf2[i & 511];
}

// ---------------- conv1 device body (untiled, transpose load) --------------
template<int CIN, int COUT, int OBLK, int LIN, int PITCH, int POUT, int NTT>
__device__ __forceinline__ void dev_conv1(int b, int oy,
        const float* __restrict__ in, const float* __restrict__ Kw,
        const float* __restrict__ bias, float* __restrict__ out) {
    constexpr int SPO = 256 / OBLK;
    constexpr int PT = (NTT < 4) ? NTT : 4;
    constexpr int NPASS = (NTT + PT - 1) / PT;
    __shared__ __align__(16) float s_in[CIN * PITCH];
    for (int idx = threadIdx.x; idx < CIN * PITCH; idx += 256) s_in[idx] = 0.f;
    __syncthreads();
    for (int idx = threadIdx.x; idx < LIN * CIN; idx += 256) {
        int p = idx / CIN, c = idx - p * CIN;
        s_in[c * PITCH + p] = in[(size_t)b * (LIN * CIN) + idx];
    }
    __syncthreads();
    int ol = threadIdx.x / SPO;
    int s  = threadIdx.x - ol * SPO;
    int o  = oy * OBLK + ol;
    float bo = bias[o];
    const float* wrow = Kw + (size_t)o * CIN * 8;
    for (int pass = 0; pass < NPASS; pass++) {
        float acc[PT][12];
#pragma unroll
        for (int tt = 0; tt < PT; tt++)
#pragma unroll
            for (int j = 0; j < 12; j++) acc[tt][j] = 0.f;
        bool vld[PT]; int tgs[PT];
#pragma unroll
        for (int tt = 0; tt < PT; tt++) {
            int ta = pass * PT + tt;
            int tg = s + SPO * ta;
            tgs[tt] = tg;
            vld[tt] = (ta < NTT) && (4 * tg < POUT);
        }
        for (int i = 0; i < CIN; i++) {
            float wa[8];
            const float4* wp = (const float4*)(wrow + (size_t)i * 8);
            *(float4*)&wa[0] = wp[0];
            *(float4*)&wa[4] = wp[1];
#pragma unroll
            for (int tt = 0; tt < PT; tt++) {
                if (vld[tt]) {
                    const float4* xr = (const float4*)&s_in[i * PITCH + 12 * tgs[tt]];
                    float xa[20];
#pragma unroll
                    for (int q = 0; q < 5; q++) *(float4*)&xa[4 * q] = xr[q];
#pragma unroll
                    for (int j = 0; j < 12; j++) {
                        float sm = acc[tt][j];
#pragma unroll
                        for (int k = 0; k < 8; k++) sm = fmaf(xa[j + k], wa[k], sm);
                        acc[tt][j] = sm;
                    }
                }
            }
        }
#pragma unroll
        for (int tt = 0; tt < PT; tt++) {
            if (vld[tt]) {
#pragma unroll
                for (int p = 0; p < 4; p++) {
                    int P = 4 * tgs[tt] + p;
                    if (P < POUT) {
                        float m = fmaxf(fmaxf(acc[tt][3 * p], acc[tt][3 * p + 1]), acc[tt][3 * p + 2]);
                        out[((size_t)b * COUT + o) * POUT + P] = fmaxf(m + bo, 0.f);
                    }
                }
            }
        }
    }
}

// ------------- tiled conv device body (seq-axis tiles, small LDS) ----------
template<int CIN, int COUT, int OBLK, int LIN, int PITCH, int TPOOL, int POUT>
__device__ __forceinline__ void dev_conv_t(int b, int oy, int tile,
        const float* __restrict__ in, const float* __restrict__ Kw,
        const float* __restrict__ bias, float* __restrict__ out) {
    constexpr int SPO = 256 / OBLK;
    constexpr int NQ = TPOOL / 4;
    constexpr int NTT = (NQ + SPO - 1) / SPO;
    constexpr int SPAN = 3 * TPOOL + 7;
    __shared__ __align__(16) float s_in[CIN * PITCH];
    int p0 = tile * TPOOL;
    int cbase = 3 * p0;
    for (int idx = threadIdx.x; idx < CIN * PITCH; idx += 256) {
        int c = idx / PITCH, p = idx - c * PITCH;
        int gp = cbase + p;
        float v = 0.f;
        if (p < SPAN && gp < LIN) v = in[((size_t)b * CIN + c) * LIN + gp];
        s_in[idx] = v;
    }
    __syncthreads();
    int ol = threadIdx.x / SPO;
    int s  = threadIdx.x - ol * SPO;
    int o  = oy * OBLK + ol;
    float bo = bias[o];
    const float* wrow = Kw + (size_t)o * CIN * 8;
    float acc[NTT][12];
#pragma unroll
    for (int tt = 0; tt < NTT; tt++)
#pragma unroll
        for (int j = 0; j < 12; j++) acc[tt][j] = 0.f;
    bool vld[NTT]; int qgs[NTT];
#pragma unroll
    for (int tt = 0; tt < NTT; tt++) {
        int qg = s + SPO * tt;
        qgs[tt] = qg;
        vld[tt] = (qg < NQ) && (p0 + 4 * qg < POUT);
    }
    for (int i = 0; i < CIN; i++) {
        float wa[8];
        const float4* wp = (const float4*)(wrow + (size_t)i * 8);
        *(float4*)&wa[0] = wp[0];
        *(float4*)&wa[4] = wp[1];
#pragma unroll
        for (int tt = 0; tt < NTT; tt++) {
            if (vld[tt]) {
                const float4* xr = (const float4*)&s_in[i * PITCH + 12 * qgs[tt]];
                float xa[20];
#pragma unroll
                for (int q = 0; q < 5; q++) *(float4*)&xa[4 * q] = xr[q];
#pragma unroll
                for (int j = 0; j < 12; j++) {
                    float sm = acc[tt][j];
#pragma unroll
                    for (int k = 0; k < 8; k++) sm = fmaf(xa[j + k], wa[k], sm);
                    acc[tt][j] = sm;
                }
            }
        }
    }
#pragma unroll
    for (int tt = 0; tt < NTT; tt++) {
        if (vld[tt]) {
#pragma unroll
            for (int p = 0; p < 4; p++) {
                int P = p0 + 4 * qgs[tt] + p;
                if (P < POUT) {
                    float m = fmaxf(fmaxf(acc[tt][3 * p], acc[tt][3 * p + 1]), acc[tt][3 * p + 2]);
                    out[((size_t)b * COUT + o) * POUT + P] = fmaxf(m + bo, 0.f);
                }
            }
        }
    }
}

// -------- K_A: pass1 edge binning (1000) || conv1 oy=0 (512) ---------------
__global__ __launch_bounds__(256) void k_A(
        const int* __restrict__ src, const int* __restrict__ dst,
        int* __restrict__ gcursor, unsigned* __restrict__ stage,
        const float* __restrict__ tgt, const float* __restrict__ K1,
        const float* __restrict__ cb1, float* __restrict__ pool1) {
    __shared__ int hcnt[NBKT];
    __shared__ int hbase[NBKT];
    int bx = blockIdx.x;
    if (bx >= 1000) {
        dev_conv1<5, 32, 16, 1000, 1008, 331, 6>(bx - 1000, 0, tgt, K1, cb1, pool1);
        return;
    }
    int e0 = bx * NEPB;
    hcnt[threadIdx.x] = 0;
    __syncthreads();
    const int4* d4 = (const int4*)(dst + e0);
    for (int i = threadIdx.x; i < NEPB / 4; i += 256) {
        int4 d = d4[i];
        atomicAdd(&hcnt[d.x / BKTN], 1);
        atomicAdd(&hcnt[d.y / BKTN], 1);
        atomicAdd(&hcnt[d.z / BKTN], 1);
        atomicAdd(&hcnt[d.w / BKTN], 1);
    }
    __syncthreads();
    hbase[threadIdx.x] = atomicAdd(&gcursor[threadIdx.x], hcnt[threadIdx.x]);
    hcnt[threadIdx.x] = 0;
    __syncthreads();
    const int4* s4 = (const int4*)(src + e0);
    for (int i = threadIdx.x; i < NEPB / 4; i += 256) {
        int4 d = d4[i];
        int4 s = s4[i];
        int ds[4] = {d.x, d.y, d.z, d.w};
        int ss[4] = {s.x, s.y, s.z, s.w};
#pragma unroll
        for (int j = 0; j < 4; j++) {
            int bkt = ds[j] / BKTN;
            int dloc = ds[j] - bkt * BKTN;
            int k = atomicAdd(&hcnt[bkt], 1);
            stage[hbase[bkt] + k] = ((unsigned)dloc << 18) | (unsigned)ss[j];
        }
    }
}

// -------- K_Bp: pass2 (256) || conv1 oy=1 (512) ----------------------------
__global__ __launch_bounds__(256) void k_Bp(
        const unsigned* __restrict__ stage, const int* __restrict__ gcursor,
        int* __restrict__ rowptr, int* __restrict__ cnt, int* __restrict__ csr,
        const float* __restrict__ x, float4* __restrict__ dt1,
        const float* __restrict__ tgt, const float* __restrict__ K1,
        const float* __restrict__ cb1, float* __restrict__ pool1) {
    __shared__ int lcnt[BKTN];
    __shared__ int lpos[BKTN];
    __shared__ int partial[256];
    __shared__ int sbase;
    int bx = blockIdx.x;
    if (bx >= NBKT) {
        dev_conv1<5, 32, 16, 1000, 1008, 331, 6>(bx - NBKT, 1, tgt, K1, cb1, pool1);
        return;
    }
    int t = threadIdx.x;
    int bkt = bx;
    int tot = gcursor[t] - t * BKTCAP;
    partial[t] = tot;
    __syncthreads();
#pragma unroll
    for (int off = 1; off < 256; off <<= 1) {
        int u = (t >= off) ? partial[t - off] : 0;
        __syncthreads();
        partial[t] += u;
        __syncthreads();
    }
    if (t == 0) sbase = (bkt == 0) ? 0 : partial[bkt - 1];
    __syncthreads();
    int base = sbase;
    int n0 = bkt * BKTN;
    int ncnt = (NA - n0 < BKTN) ? (NA - n0) : BKTN;
    int eBeg = bkt * BKTCAP;
    int eCnt = gcursor[bkt] - eBeg;
    for (int i = t; i < BKTN; i += 256) lcnt[i] = 0;
    __syncthreads();
    for (int i = t; i < eCnt; i += 256)
        atomicAdd(&lcnt[stage[eBeg + i] >> 18], 1);
    __syncthreads();
    int mysum = 0;
#pragma unroll
    for (int j = 0; j < 4; j++) {
        int node = 4 * t + j;
        if (node < ncnt) mysum += lcnt[node];
    }
    partial[t] = mysum;
    __syncthreads();
#pragma unroll
    for (int off = 1; off < 256; off <<= 1) {
        int u = (t >= off) ? partial[t - off] : 0;
        __syncthreads();
        partial[t] += u;
        __syncthreads();
    }
    int running = partial[t] - mysum;
#pragma unroll
    for (int j = 0; j < 4; j++) {
        int node = 4 * t + j;
        if (node < ncnt) {
            lpos[node] = running;
            rowptr[n0 + node] = base + running;
            cnt[n0 + node] = lcnt[node];
            running += lcnt[node];
        }
    }
    __syncthreads();
    for (int i = t; i < eCnt; i += 256) {
        unsigned v = stage[eBeg + i];
        int dloc = v >> 18;
        int s = v & 0x3FFFF;
        int k = atomicAdd(&lpos[dloc], 1);
        csr[base + k] = s;
    }
    for (int i = t; i < ncnt; i += 256) {
        int n = n0 + i;
        float4 p = ((const float4*)x)[n];
        float dv = rsqrtf((float)lcnt[i] + 1.0f);
        dt1[n] = make_float4(dv * p.x, dv * p.y, dv * p.z, dv * p.w);
    }
}

// -------- K_B: conv2 tiled (1536) || gather1+W1 -> dt2 (782) ---------------
__global__ __launch_bounds__(256) void k_B(
        const float* __restrict__ pool1, const float* __restrict__ K2,
        const float* __restrict__ cb2, float* __restrict__ pool2,
        const float4* __restrict__ dt1, const int* __restrict__ rowptr,
        const int* __restrict__ cnt, const int* __restrict__ csr,
        const float* __restrict__ W1, const float* __restrict__ b1,
        float4* __restrict__ dt2) {
    int bx = blockIdx.x;
    if (bx < 1536) {
        dev_conv_t<32, 64, 64, 331, 116, 36, 108>(bx & 511, 0, bx >> 9, pool1, K2, cb2, pool2);
        return;
    }
    __shared__ float sW[16];
    if (threadIdx.x < 16) sW[threadIdx.x] = W1[threadIdx.x];
    __syncthreads();
    int n = (bx - 1536) * 256 + threadIdx.x;
    if (n >= NA) return;
    int cn = cnt[n];
    float dv = rsqrtf((float)cn + 1.0f);
    const int* row = csr + rowptr[n];
    float4 acc = dt1[n];
    int e = 0;
    for (; e + 3 < cn; e += 4) {
        int i0 = row[e], i1 = row[e + 1], i2 = row[e + 2], i3 = row[e + 3];
        float4 v0 = dt1[i0], v1 = dt1[i1], v2 = dt1[i2], v3 = dt1[i3];
        acc.x += (v0.x + v1.x) + (v2.x + v3.x);
        acc.y += (v0.y + v1.y) + (v2.y + v3.y);
        acc.z += (v0.z + v1.z) + (v2.z + v3.z);
        acc.w += (v0.w + v1.w) + (v2.w + v3.w);
    }
    for (; e < cn; e++) {
        float4 v = dt1[row[e]];
        acc.x += v.x; acc.y += v.y; acc.z += v.z; acc.w += v.w;
    }
    const float4 bq = *(const float4*)b1;
    float a[4] = {acc.x, acc.y, acc.z, acc.w};
    float bb[4] = {bq.x, bq.y, bq.z, bq.w};
    float o[4];
#pragma unroll
    for (int f = 0; f < 4; f++) {
        float s = 0.f;
#pragma unroll
        for (int k = 0; k < 4; k++) s = fmaf(a[k], sW[k * 4 + f], s);
        o[f] = dv * fmaxf(fmaf(dv, s, bb[f]), 0.f);   // dt2 = dv*relu(...)
    }
    dt2[n] = make_float4(o[0], o[1], o[2], o[3]);
}

// -------- K_C: conv3 tiled (1024) || gather2+W2 -> dt3 fp16 (782) ----------
__global__ __launch_bounds__(256) void k_C(
        const float* __restrict__ pool2, const float* __restrict__ K3,
        const float* __restrict__ cb3, float* __restrict__ pool3,
        const float4* __restrict__ dt2, const int* __restrict__ rowptr,
        const int* __restrict__ cnt, const int* __restrict__ csr,
        const float* __restrict__ W2, const float* __restrict__ b2,
        uint4* __restrict__ dt3) {
    int bx = blockIdx.x;
    if (bx < 1024) {
        dev_conv_t<64, 128, 128, 108, 68, 20, 33>(bx & 511, 0, bx >> 9, pool2, K3, cb3, pool3);
        return;
    }
    __shared__ float sW[32];
    if (threadIdx.x < 32) sW[threadIdx.x] = W2[threadIdx.x];
    __syncthreads();
    int n = (bx - 1024) * 256 + threadIdx.x;
    if (n >= NA) return;
    int cn = cnt[n];
    float dv = rsqrtf((float)cn + 1.0f);
    const int* row = csr + rowptr[n];
    float4 acc = dt2[n];
    int e = 0;
    for (; e + 3 < cn; e += 4) {
        int i0 = row[e], i1 = row[e + 1], i2 = row[e + 2], i3 = row[e + 3];
        float4 v0 = dt2[i0], v1 = dt2[i1], v2 = dt2[i2], v3 = dt2[i3];
        acc.x += (v0.x + v1.x) + (v2.x + v3.x);
        acc.y += (v0.y + v1.y) + (v2.y + v3.y);
        acc.z += (v0.z + v1.z) + (v2.z + v3.z);
        acc.w += (v0.w + v1.w) + (v2.w + v3.w);
    }
    for (; e < cn; e++) {
        float4 v = dt2[row[e]];
        acc.x += v.x; acc.y += v.y; acc.z += v.z; acc.w += v.w;
    }
    float a[4] = {acc.x, acc.y, acc.z, acc.w};
    float o[8];
#pragma unroll
    for (int f = 0; f < 8; f++) {
        float s = 0.f;
#pragma unroll
        for (int k = 0; k < 4; k++) s = fmaf(a[k], sW[k * 8 + f], s);
        o[f] = dv * fmaxf(fmaf(dv, s, b2[f]), 0.f);   // dt3 = dv*relu(...)
    }
    dt3[n] = make_uint4(f2h(o[0], o[1]), f2h(o[2], o[3]),
                        f2h(o[4], o[5]), f2h(o[6], o[7]));
}

// -------- K_D: gather3(fp16)+W3+segmax (782) || mean+Wxt -> cx (64) --------
__global__ __launch_bounds__(256) void k_D(
        const uint4* __restrict__ dt3, const int* __restrict__ rowptr,
        const int* __restrict__ cnt, const int* __restrict__ csr,
        const float* __restrict__ W3, const float* __restrict__ b3,
        const int* __restrict__ batch, unsigned* __restrict__ g,
        const float* __restrict__ pool3, const float* __restrict__ Wxt,
        const float* __restrict__ bxt, float* __restrict__ cx) {
    int bx = blockIdx.x;
    if (bx >= 782) {
        // mean over 33 taps then @Wxt (+relu): 8 batches/block
        __shared__ float sa[8 * 128];
        int b0 = (bx - 782) * 8;
        for (int t = threadIdx.x; t < 8 * 128; t += 256) {
            int gg = t >> 7, k = t & 127;
            const float* r = pool3 + ((size_t)(b0 + gg) * 128 + k) * 33;
            float s = 0.f;
#pragma unroll
            for (int p = 0; p < 33; p++) s += r[p];
            sa[t] = s * (1.f / 33.f);
        }
        __syncthreads();
        int j = threadIdx.x;
        if (j >= 128) return;
        float bj = bxt[j];
        float acc[8];
#pragma unroll
        for (int gg = 0; gg < 8; gg++) acc[gg] = bj;
#pragma unroll 4
        for (int k = 0; k < 128; k++) {
            float w = Wxt[(size_t)k * 128 + j];
#pragma unroll
            for (int gg = 0; gg < 8; gg++) acc[gg] = fmaf(sa[gg * 128 + k], w, acc[gg]);
        }
#pragma unroll
        for (int gg = 0; gg < 8; gg++)
            cx[(size_t)(b0 + gg) * 128 + j] = fmaxf(acc[gg], 0.f);
        return;
    }
    __shared__ float sW[128];
    __shared__ unsigned sg[32];
    __shared__ int sbmin;
    int id = bx;                        // 256 nodes per block
    if (threadIdx.x < 128) sW[threadIdx.x] = W3[threadIdx.x];
    if (threadIdx.x < 32) sg[threadIdx.x] = 0u;
    if (threadIdx.x == 0) sbmin = batch[id * 256];
    __syncthreads();
    int n = id * 256 + threadIdx.x;
    if (n < NA) {
        int cn = cnt[n];
        float dv = rsqrtf((float)cn + 1.0f);
        const int* row = csr + rowptr[n];
        uint4 sv = dt3[n];
        float4 lo = h4f(sv.x, sv.y), hi = h4f(sv.z, sv.w);
        float a0 = lo.x, a1 = lo.y, a2 = lo.z, a3 = lo.w;
        float a4 = hi.x, a5 = hi.y, a6 = hi.z, a7 = hi.w;
        int e = 0;
        for (; e + 3 < cn; e += 4) {
            uint4 p0 = dt3[row[e]],     p1 = dt3[row[e + 1]];
            uint4 p2 = dt3[row[e + 2]], p3 = dt3[row[e + 3]];
            float4 l0 = h4f(p0.x, p0.y), h0 = h4f(p0.z, p0.w);
            float4 l1 = h4f(p1.x, p1.y), h1 = h4f(p1.z, p1.w);
            float4 l2 = h4f(p2.x, p2.y), h2 = h4f(p2.z, p2.w);
            float4 l3 = h4f(p3.x, p3.y), h3v = h4f(p3.z, p3.w);
            a0 += (l0.x + l1.x) + (l2.x + l3.x);
            a1 += (l0.y + l1.y) + (l2.y + l3.y);
            a2 += (l0.z + l1.z) + (l2.z + l3.z);
            a3 += (l0.w + l1.w) + (l2.w + l3.w);
            a4 += (h0.x + h1.x) + (h2.x + h3v.x);
            a5 += (h0.y + h1.y) + (h2.y + h3v.y);
            a6 += (h0.z + h1.z) + (h2.z + h3v.z);
            a7 += (h0.w + h1.w) + (h2.w + h3v.w);
        }
        for (; e < cn; e++) {
            uint4 p = dt3[row[e]];
            float4 l = h4f(p.x, p.y), h = h4f(p.z, p.w);
            a0 += l.x; a1 += l.y; a2 += l.z; a3 += l.w;
            a4 += h.x; a5 += h.y; a6 += h.z; a7 += h.w;
        }
        float af[8] = {a0, a1, a2, a3, a4, a5, a6, a7};
        int rb = batch[n] - sbmin;
        if (rb > 1) rb = 1;
#pragma unroll
        for (int f = 0; f < 16; f++) {
            float s = 0.f;
#pragma unroll
            for (int k = 0; k < 8; k++) s = fmaf(af[k], sW[k * 16 + f], s);
            float r = fmaxf(fmaf(dv, s, b3[f]), 0.f);
            atomicMax(&sg[rb * 16 + f], __float_as_uint(r));
        }
    }
    __syncthreads();
    if (threadIdx.x < 32) {
        unsigned v = sg[threadIdx.x];
        int rb2 = threadIdx.x >> 4, f = threadIdx.x & 15;
        int bbn = sbmin + rb2;
        if (v != 0u && bbn < NB) atomicMax(&g[bbn * 16 + f], v);
    }
}

// -------- head: g@Wg1 -> gp1 (relu), 256 blocks ----------------------------
__global__ __launch_bounds__(256) void k_head_g(
        const float* __restrict__ g, const float* __restrict__ Wg1,
        const float* __restrict__ bg1, float* __restrict__ gp1) {
    __shared__ float sa[8 * 16];
    int bx = blockIdx.x;
    int b0 = (bx >> 2) * 8;
    if (threadIdx.x < 128)
        sa[threadIdx.x] = g[b0 * 16 + threadIdx.x];
    __syncthreads();
    int j = (bx & 3) * 256 + threadIdx.x;
    float bj = bg1[j];
    float acc[8];
#pragma unroll
    for (int gg = 0; gg < 8; gg++) acc[gg] = bj;
#pragma unroll
    for (int k = 0; k < 16; k++) {
        float w = Wg1[(size_t)k * 1024 + j];
#pragma unroll
        for (int gg = 0; gg < 8; gg++) acc[gg] = fmaf(sa[gg * 16 + k], w, acc[gg]);
    }
#pragma unroll
    for (int gg = 0; gg < 8; gg++)
        gp1[(size_t)(b0 + gg) * 1024 + j] = fmaxf(acc[gg], 0.f);
}

// -------- gvec += (gp1 K-slice)@Wg2 ; K-split x4, fp32 atomicAdd -----------
__global__ __launch_bounds__(256) void k_gvec_ks(
        const float* __restrict__ gp1, const float* __restrict__ Wg2,
        float* __restrict__ gvec) {
    __shared__ float sa[8 * 256];       // 8 KB
    int k0 = blockIdx.x * 256;          // K-split 0..3
    int b0 = blockIdx.y * 8;
    for (int t = threadIdx.x; t < 8 * 256; t += 256) {
        int gg = t >> 8, k = t & 255;
        sa[t] = gp1[(size_t)(b0 + gg) * 1024 + k0 + k];
    }
    __syncthreads();
    int j = threadIdx.x;
    if (j >= 128) return;
    float acc[8];
#pragma unroll
    for (int gg = 0; gg < 8; gg++) acc[gg] = 0.f;
#pragma unroll 4
    for (int k = 0; k < 256; k++) {
        float w = Wg2[(size_t)(k0 + k) * 128 + j];
#pragma unroll
        for (int gg = 0; gg < 8; gg++) acc[gg] = fmaf(sa[gg * 256 + k], w, acc[gg]);
    }
#pragma unroll
    for (int gg = 0; gg < 8; gg++)
        atomicAdd(&gvec[(size_t)(b0 + gg) * 128 + j], acc[gg]);
}

// -------- dense with concatenated input [gvec | cx] -> relu -> xf1 ---------
template<int KA, int KB2, int BGRP, bool RELU>
__global__ __launch_bounds__(256) void k_dense_cat_g(
        const float* __restrict__ A1, const float* __restrict__ A2,
        const float* __restrict__ W, const float* __restrict__ bias,
        float* __restrict__ out, int ncols) {
    constexpr int K = KA + KB2;
    __shared__ float sa[BGRP * K];
    int b0 = blockIdx.y * BGRP;
    for (int t = threadIdx.x; t < BGRP * K; t += 256) {
        int gg = t / K, k = t - gg * K;
        sa[t] = (k < KA) ? A1[(size_t)(b0 + gg) * KA + k]
                         : A2[(size_t)(b0 + gg) * KB2 + (k - KA)];
    }
    __syncthreads();
    int j = blockIdx.x * 256 + threadIdx.x;
    if (j >= ncols) return;
    float bj = bias[j];
    float acc[BGRP];
#pragma unroll
    for (int gg = 0; gg < BGRP; gg++) acc[gg] = bj;
#pragma unroll 4
    for (int k = 0; k < K; k++) {
        float w = W[(size_t)k * ncols + j];
#pragma unroll
        for (int gg = 0; gg < BGRP; gg++) acc[gg] = fmaf(sa[gg * K + k], w, acc[gg]);
    }
#pragma unroll
    for (int gg = 0; gg < BGRP; gg++) {
        float v = acc[gg];
        if (RELU) v = fmaxf(v, 0.f);
        out[(size_t)(b0 + gg) * ncols + j] = v;
    }
}

// -------- xf2 += (xf1 K-slice)@Wf2 ; K-split x2, j-split x2 ----------------
// relu deferred to k_dense_out read
__global__ __launch_bounds__(256) void k_xf2_ks(
        const float* __restrict__ xf1, const float* __restrict__ Wf2,
        float* __restrict__ xf2) {
    __shared__ float sa[8 * 512];       // 16 KB
    int jb = blockIdx.x & 1;
    int k0 = (blockIdx.x >> 1) * 512;
    int b0 = blockIdx.y * 8;
    for (int t = threadIdx.x; t < 8 * 512; t += 256) {
        int gg = t >> 9, k = t & 511;
        sa[t] = xf1[(size_t)(b0 + gg) * 1024 + k0 + k];
    }
    __syncthreads();
    int j = jb * 256 + threadIdx.x;
    float acc[8];
#pragma unroll
    for (int gg = 0; gg < 8; gg++) acc[gg] = 0.f;
#pragma unroll 4
    for (int k = 0; k < 512; k++) {
        float w = Wf2[(size_t)(k0 + k) * 512 + j];
#pragma unroll
        for (int gg = 0; gg < 8; gg++) acc[gg] = fmaf(sa[gg * 512 + k], w, acc[gg]);
    }
#pragma unroll
    for (int gg = 0; gg < 8; gg++)
        atomicAdd(&xf2[(size_t)(b0 + gg) * 512 + j], acc[gg]);
}

// final 512->2 layer; applies the deferred relu on xf2
__global__ __launch_bounds__(256) void k_dense_out(
        const float* __restrict__ A, const float* __restrict__ W,
        const float* __restrict__ bias, float* __restrict__ out) {
    int idx = blockIdx.x * 256 + threadIdx.x;
    if (idx >= NB * 2) return;
    int b = idx >> 1, j = idx & 1;
    float s = bias[j];
#pragma unroll 8
    for (int k = 0; k < 512; k++)
        s = fmaf(fmaxf(A[b * 512 + k], 0.f), W[k * 2 + j], s);
    out[idx] = s;
}

extern "C" void kernel_launch(void* const* d_in, const int* in_sizes, int n_in,
                              void* d_out, int out_size, void* d_ws, size_t ws_size,
                              hipStream_t stream) {
    (void)in_sizes; (void)n_in; (void)out_size; (void)ws_size;
    const float* x   = (const float*)d_in[0];
    const int*  ei   = (const int*)d_in[1];
    const int*  batch= (const int*)d_in[2];
    const float* tgt = (const float*)d_in[3];
    const float* W1  = (const float*)d_in[4];  const float* b1  = (const float*)d_in[5];
    const float* W2  = (const float*)d_in[6];  const float* b2  = (const float*)d_in[7];
    const float* W3  = (const float*)d_in[8];  const float* b3  = (const float*)d_in[9];
    const float* Wg1 = (const float*)d_in[10]; const float* bg1 = (const float*)d_in[11];
    const float* Wg2 = (const float*)d_in[12]; const float* bg2 = (const float*)d_in[13];
    const float* K1  = (const float*)d_in[14]; const float* cb1 = (const float*)d_in[15];
    const float* K2  = (const float*)d_in[16]; const float* cb2 = (const float*)d_in[17];
    const float* K3  = (const float*)d_in[18]; const float* cb3 = (const float*)d_in[19];
    const float* Wxt = (const float*)d_in[20]; const float* bxt = (const float*)d_in[21];
    const float* Wf1 = (const float*)d_in[22]; const float* bf1 = (const float*)d_in[23];
    const float* Wf2 = (const float*)d_in[24]; const float* bf2 = (const float*)d_in[25];
    const float* Wo  = (const float*)d_in[26]; const float* bo  = (const float*)d_in[27];
    const int* srcp = ei;        // edge_index[0]
    const int* dstp = ei + NE;   // edge_index[1]

    float* ws = (float*)d_ws;
    float4* dt1 = (float4*)ws; ws += (size_t)NA * 4;   // dis*x          (3.2 MB)
    float4* dt2 = (float4*)ws; ws += (size_t)NA * 4;   // dis*out1       (3.2 MB)
    uint4*  dt3 = (uint4*)ws;  ws += (size_t)NA * 4;   // dis*out2 fp16  (3.2 MB)
    float* g     = ws; ws += NB * 16;
    float* gp1   = ws; ws += NB * 1024;
    float* gvec  = ws; ws += NB * 128;
    float* cx    = ws; ws += NB * 128;
    float* xf1   = ws; ws += NB * 1024;
    float* xf2   = ws; ws += NB * 512;
    float* pool1 = ws; ws += (size_t)NB * 32 * 331;   // 5.42M
    float* pool2 = ws; ws += (size_t)NB * 64 * 108;   // 3.54M
    float* pool3 = ws; ws += (size_t)NB * 128 * 33;   // 2.16M
    int*   cnt    = (int*)ws; ws += NA;
    int*   rowptr = (int*)ws; ws += NA;
    int*   csr    = (int*)ws; ws += NE;               // compact CSR
    int*   gcursor= (int*)ws; ws += NBKT;
    unsigned* stage = (unsigned*)ws; ws += (size_t)NBKT * BKTCAP; // 16.8 MB, OWN
    // region (conv1 writes pool1 concurrently with pass1 writing stage)

    dim3 blk(256);

    k_init<<<1024, blk, 0, stream>>>((unsigned*)g, gcursor, gvec, bg2, xf2, bf2);
    // K_A: pass1 (1000) || conv1 oy=0 (512)
    k_A<<<1512, blk, 0, stream>>>(srcp, dstp, gcursor, stage, tgt, K1, cb1, pool1);
    // K_Bp: pass2 (256) || conv1 oy=1 (512)
    k_Bp<<<768, blk, 0, stream>>>(stage, gcursor, rowptr, cnt, csr, x, dt1,
                                  tgt, K1, cb1, pool1);
    // K_B: conv2 tiled (1536) || gather1+W1 (782)
    k_B<<<2318, blk, 0, stream>>>(pool1, K2, cb2, pool2,
                                  dt1, rowptr, cnt, csr, W1, b1, dt2);
    // K_C: conv3 tiled (1024) || gather2+W2 (782)
    k_C<<<1806, blk, 0, stream>>>(pool2, K3, cb3, pool3,
                                  dt2, rowptr, cnt, csr, W2, b2, dt3);
    // K_D: gather3(fp16)+W3+segmax (782) || mean+Wxt (64)
    k_D<<<846, blk, 0, stream>>>(dt3, rowptr, cnt, csr, W3, b3,
                                 batch, (unsigned*)g, pool3, Wxt, bxt, cx);

    // dense head (parallelism-first: every kernel >=256 blocks)
    k_head_g<<<256, blk, 0, stream>>>(g, Wg1, bg1, gp1);
    k_gvec_ks<<<dim3(4, 64), blk, 0, stream>>>(gp1, Wg2, gvec);
    k_dense_cat_g<128, 128, 8, true><<<dim3(4, 64), blk, 0, stream>>>(gvec, cx, Wf1, bf1, xf1, 1024);
    k_xf2_ks<<<dim3(4, 64), blk, 0, stream>>>(xf1, Wf2, xf2);
    k_dense_out<<<4, blk, 0, stream>>>(xf2, Wo, bo, (float*)d_out);
}

// Round 14
// 591.722 us; speedup vs baseline: 1.4272x; 1.0551x over previous
//
#include <hip/hip_runtime.h>
#include <hip/hip_fp16.h>
#include <cstddef>

#define NA 200000
#define NE 3200000
#define NB 512
#define NBKT 256          // dst-range buckets
#define BKTN 782          // nodes per bucket
#define BKTCAP 16384      // stage capacity per bucket (exp 12500, sigma ~111)
#define NEPB 3200         // edges per pass-1 block (1000*3200 = NE)

// ---------------- fp16 helpers ----------------
typedef _Float16 hv2 __attribute__((ext_vector_type(2)));
union UH2 { unsigned u; __half2 h; hv2 v; };
__device__ __forceinline__ float4 h4f(unsigned a, unsigned b) {
    UH2 x, y; x.u = a; y.u = b;
    float2 fa = __half22float2(x.h), fb = __half22float2(y.h);
    return make_float4(fa.x, fa.y, fb.x, fb.y);
}
__device__ __forceinline__ unsigned f2h(float a, float b) {
    UH2 r; r.h = __float22half2_rn(make_float2(a, b));
    return r.u;
}

// -------- init: g=0, gcursor, gvec<-bg2, xf2<-bf2 (atomic accumulators) ----
__global__ void k_init(unsigned* g, int* gcursor,
                       float* gvec, const float* __restrict__ bg2,
                       float* xf2, const float* __restrict__ bf2) {
    int i = blockIdx.x * blockDim.x + threadIdx.x;
    if (i < NB * 16) g[i] = 0u;
    if (i < NBKT) gcursor[i] = i * BKTCAP;
    if (i < NB * 128) gvec[i] = bg2[i & 127];
    if (i < NB * 512) xf2[i] = bf2[i & 511];
}

// ------- conv1 device body (fp32 LDS/compute, fp16 output) -----------------
template<int CIN, int COUT, int OBLK, int LIN, int PITCH, int POUT, int NTT>
__device__ __forceinline__ void dev_conv1(int b, int oy,
        const float* __restrict__ in, const float* __restrict__ Kw,
        const float* __restrict__ bias, __half* __restrict__ out) {
    constexpr int SPO = 256 / OBLK;
    constexpr int PT = (NTT < 4) ? NTT : 4;
    constexpr int NPASS = (NTT + PT - 1) / PT;
    __shared__ __align__(16) float s_in[CIN * PITCH];
    for (int idx = threadIdx.x; idx < CIN * PITCH; idx += 256) s_in[idx] = 0.f;
    __syncthreads();
    for (int idx = threadIdx.x; idx < LIN * CIN; idx += 256) {
        int p = idx / CIN, c = idx - p * CIN;
        s_in[c * PITCH + p] = in[(size_t)b * (LIN * CIN) + idx];
    }
    __syncthreads();
    int ol = threadIdx.x / SPO;
    int s  = threadIdx.x - ol * SPO;
    int o  = oy * OBLK + ol;
    float bo = bias[o];
    const float* wrow = Kw + (size_t)o * CIN * 8;
    for (int pass = 0; pass < NPASS; pass++) {
        float acc[PT][12];
#pragma unroll
        for (int tt = 0; tt < PT; tt++)
#pragma unroll
            for (int j = 0; j < 12; j++) acc[tt][j] = 0.f;
        bool vld[PT]; int tgs[PT];
#pragma unroll
        for (int tt = 0; tt < PT; tt++) {
            int ta = pass * PT + tt;
            int tg = s + SPO * ta;
            tgs[tt] = tg;
            vld[tt] = (ta < NTT) && (4 * tg < POUT);
        }
        for (int i = 0; i < CIN; i++) {
            float wa[8];
            const float4* wp = (const float4*)(wrow + (size_t)i * 8);
            *(float4*)&wa[0] = wp[0];
            *(float4*)&wa[4] = wp[1];
#pragma unroll
            for (int tt = 0; tt < PT; tt++) {
                if (vld[tt]) {
                    const float4* xr = (const float4*)&s_in[i * PITCH + 12 * tgs[tt]];
                    float xa[20];
#pragma unroll
                    for (int q = 0; q < 5; q++) *(float4*)&xa[4 * q] = xr[q];
#pragma unroll
                    for (int j = 0; j < 12; j++) {
                        float sm = acc[tt][j];
#pragma unroll
                        for (int k = 0; k < 8; k++) sm = fmaf(xa[j + k], wa[k], sm);
                        acc[tt][j] = sm;
                    }
                }
            }
        }
#pragma unroll
        for (int tt = 0; tt < PT; tt++) {
            if (vld[tt]) {
#pragma unroll
                for (int p = 0; p < 4; p++) {
                    int P = 4 * tgs[tt] + p;
                    if (P < POUT) {
                        float m = fmaxf(fmaxf(acc[tt][3 * p], acc[tt][3 * p + 1]), acc[tt][3 * p + 2]);
                        out[((size_t)b * COUT + o) * POUT + P] = __float2half(fmaxf(m + bo, 0.f));
                    }
                }
            }
        }
    }
}

// ------- fp16 dot2 conv body: input fp16, two LDS copies (aligned+shifted),
//         v_dot2_f32_f16 inner loop (2 MACs/instr, fp32 accumulate) ---------
// COUT == OBLK (one oy). OUTH: write fp16 (else fp32).
template<int CIN, int COUT, int LIN, int PITCH, int TPOOL, int POUT, bool OUTH>
__device__ __forceinline__ void dev_conv_h(int b, int tile,
        const __half* __restrict__ in, const float* __restrict__ Kw,
        const float* __restrict__ bias, void* __restrict__ outv) {
    constexpr int SPO = 256 / COUT;
    constexpr int NQ = TPOOL / 4;
    constexpr int NTT = (NQ + SPO - 1) / SPO;
    constexpr int SPAN = 3 * TPOOL + 7;
    constexpr int PH = PITCH / 2;               // u32 per row
    __shared__ __align__(16) __half sA[CIN * PITCH];
    __shared__ __align__(16) __half sB[CIN * PITCH];
    int p0 = tile * TPOOL;
    int cbase = 3 * p0;
    for (int idx = threadIdx.x; idx < CIN * PITCH; idx += 256) {
        int c = idx / PITCH, p = idx - c * PITCH;
        int gp = cbase + p;
        __half v = __float2half(0.f);
        if (p < SPAN && gp < LIN) v = in[((size_t)b * CIN + c) * LIN + gp];
        sA[idx] = v;
    }
    __syncthreads();
    for (int idx = threadIdx.x; idx < CIN * PITCH; idx += 256) {
        int c = idx / PITCH, p = idx - c * PITCH;
        sB[idx] = (p + 1 < PITCH) ? sA[c * PITCH + p + 1] : __float2half(0.f);
    }
    __syncthreads();
    const unsigned* A32 = (const unsigned*)sA;
    const unsigned* B32 = (const unsigned*)sB;
    int ol = threadIdx.x / SPO;
    int s  = threadIdx.x - ol * SPO;
    int o  = ol;
    float bo = bias[o];
    const float* wrow = Kw + (size_t)o * CIN * 8;
    float acc[NTT][12];
#pragma unroll
    for (int tt = 0; tt < NTT; tt++)
#pragma unroll
        for (int j = 0; j < 12; j++) acc[tt][j] = 0.f;
    bool vld[NTT]; int qgs[NTT];
#pragma unroll
    for (int tt = 0; tt < NTT; tt++) {
        int qg = s + SPO * tt;
        qgs[tt] = qg;
        vld[tt] = (qg < NQ) && (p0 + 4 * qg < POUT);
    }
    for (int i = 0; i < CIN; i++) {
        const float4* wp4 = (const float4*)(wrow + (size_t)i * 8);
        float4 wlo = wp4[0], whi = wp4[1];
        UH2 w[4];
        w[0].u = f2h(wlo.x, wlo.y);
        w[1].u = f2h(wlo.z, wlo.w);
        w[2].u = f2h(whi.x, whi.y);
        w[3].u = f2h(whi.z, whi.w);
#pragma unroll
        for (int tt = 0; tt < NTT; tt++) {
            if (!vld[tt]) continue;
            int base = i * PH + 6 * qgs[tt];     // T/2, T = 12*qg
            unsigned ua[9], ub[9];
#pragma unroll
            for (int m = 0; m < 9; m++) { ua[m] = A32[base + m]; ub[m] = B32[base + m]; }
#pragma unroll
            for (int jj = 0; jj < 6; jj++) {
                float se = acc[tt][2 * jj], so = acc[tt][2 * jj + 1];
#pragma unroll
                for (int r = 0; r < 4; r++) {
                    UH2 xa; xa.u = ua[jj + r];
                    UH2 xb; xb.u = ub[jj + r];
                    se = __builtin_amdgcn_fdot2(xa.v, w[r].v, se, false);
                    so = __builtin_amdgcn_fdot2(xb.v, w[r].v, so, false);
                }
                acc[tt][2 * jj] = se; acc[tt][2 * jj + 1] = so;
            }
        }
    }
#pragma unroll
    for (int tt = 0; tt < NTT; tt++) {
        if (vld[tt]) {
#pragma unroll
            for (int p = 0; p < 4; p++) {
                int P = p0 + 4 * qgs[tt] + p;
                if (P < POUT) {
                    float m = fmaxf(fmaxf(acc[tt][3 * p], acc[tt][3 * p + 1]), acc[tt][3 * p + 2]);
                    float r = fmaxf(m + bo, 0.f);
                    if (OUTH) ((__half*)outv)[((size_t)b * COUT + o) * POUT + P] = __float2half(r);
                    else      ((float*)outv)[((size_t)b * COUT + o) * POUT + P] = r;
                }
            }
        }
    }
}

// -------- K_A: pass1 edge binning (1000) || conv1 oy=0 (512) ---------------
__global__ __launch_bounds__(256) void k_A(
        const int* __restrict__ src, const int* __restrict__ dst,
        int* __restrict__ gcursor, unsigned* __restrict__ stage,
        const float* __restrict__ tgt, const float* __restrict__ K1,
        const float* __restrict__ cb1, __half* __restrict__ pool1) {
    __shared__ int hcnt[NBKT];
    __shared__ int hbase[NBKT];
    int bx = blockIdx.x;
    if (bx >= 1000) {
        dev_conv1<5, 32, 16, 1000, 1008, 331, 6>(bx - 1000, 0, tgt, K1, cb1, pool1);
        return;
    }
    int e0 = bx * NEPB;
    hcnt[threadIdx.x] = 0;
    __syncthreads();
    const int4* d4 = (const int4*)(dst + e0);
    for (int i = threadIdx.x; i < NEPB / 4; i += 256) {
        int4 d = d4[i];
        atomicAdd(&hcnt[d.x / BKTN], 1);
        atomicAdd(&hcnt[d.y / BKTN], 1);
        atomicAdd(&hcnt[d.z / BKTN], 1);
        atomicAdd(&hcnt[d.w / BKTN], 1);
    }
    __syncthreads();
    hbase[threadIdx.x] = atomicAdd(&gcursor[threadIdx.x], hcnt[threadIdx.x]);
    hcnt[threadIdx.x] = 0;
    __syncthreads();
    const int4* s4 = (const int4*)(src + e0);
    for (int i = threadIdx.x; i < NEPB / 4; i += 256) {
        int4 d = d4[i];
        int4 s = s4[i];
        int ds[4] = {d.x, d.y, d.z, d.w};
        int ss[4] = {s.x, s.y, s.z, s.w};
#pragma unroll
        for (int j = 0; j < 4; j++) {
            int bkt = ds[j] / BKTN;
            int dloc = ds[j] - bkt * BKTN;
            int k = atomicAdd(&hcnt[bkt], 1);
            stage[hbase[bkt] + k] = ((unsigned)dloc << 18) | (unsigned)ss[j];
        }
    }
}

// -------- K_Bp: pass2 (256) || conv1 oy=1 (512) ----------------------------
__global__ __launch_bounds__(256) void k_Bp(
        const unsigned* __restrict__ stage, const int* __restrict__ gcursor,
        int* __restrict__ rowptr, int* __restrict__ cnt, int* __restrict__ csr,
        const float* __restrict__ x, float4* __restrict__ dt1,
        const float* __restrict__ tgt, const float* __restrict__ K1,
        const float* __restrict__ cb1, __half* __restrict__ pool1) {
    __shared__ int lcnt[BKTN];
    __shared__ int lpos[BKTN];
    __shared__ int partial[256];
    __shared__ int sbase;
    int bx = blockIdx.x;
    if (bx >= NBKT) {
        dev_conv1<5, 32, 16, 1000, 1008, 331, 6>(bx - NBKT, 1, tgt, K1, cb1, pool1);
        return;
    }
    int t = threadIdx.x;
    int bkt = bx;
    int tot = gcursor[t] - t * BKTCAP;
    partial[t] = tot;
    __syncthreads();
#pragma unroll
    for (int off = 1; off < 256; off <<= 1) {
        int u = (t >= off) ? partial[t - off] : 0;
        __syncthreads();
        partial[t] += u;
        __syncthreads();
    }
    if (t == 0) sbase = (bkt == 0) ? 0 : partial[bkt - 1];
    __syncthreads();
    int base = sbase;
    int n0 = bkt * BKTN;
    int ncnt = (NA - n0 < BKTN) ? (NA - n0) : BKTN;
    int eBeg = bkt * BKTCAP;
    int eCnt = gcursor[bkt] - eBeg;
    for (int i = t; i < BKTN; i += 256) lcnt[i] = 0;
    __syncthreads();
    for (int i = t; i < eCnt; i += 256)
        atomicAdd(&lcnt[stage[eBeg + i] >> 18], 1);
    __syncthreads();
    int mysum = 0;
#pragma unroll
    for (int j = 0; j < 4; j++) {
        int node = 4 * t + j;
        if (node < ncnt) mysum += lcnt[node];
    }
    partial[t] = mysum;
    __syncthreads();
#pragma unroll
    for (int off = 1; off < 256; off <<= 1) {
        int u = (t >= off) ? partial[t - off] : 0;
        __syncthreads();
        partial[t] += u;
        __syncthreads();
    }
    int running = partial[t] - mysum;
#pragma unroll
    for (int j = 0; j < 4; j++) {
        int node = 4 * t + j;
        if (node < ncnt) {
            lpos[node] = running;
            rowptr[n0 + node] = base + running;
            cnt[n0 + node] = lcnt[node];
            running += lcnt[node];
        }
    }
    __syncthreads();
    for (int i = t; i < eCnt; i += 256) {
        unsigned v = stage[eBeg + i];
        int dloc = v >> 18;
        int s = v & 0x3FFFF;
        int k = atomicAdd(&lpos[dloc], 1);
        csr[base + k] = s;
    }
    for (int i = t; i < ncnt; i += 256) {
        int n = n0 + i;
        float4 p = ((const float4*)x)[n];
        float dv = rsqrtf((float)lcnt[i] + 1.0f);
        dt1[n] = make_float4(dv * p.x, dv * p.y, dv * p.z, dv * p.w);
    }
}

// -------- K_B: conv2 dot2 (1536) || gather1+W1 -> dt2 (782) ----------------
__global__ __launch_bounds__(256) void k_B(
        const __half* __restrict__ pool1, const float* __restrict__ K2,
        const float* __restrict__ cb2, __half* __restrict__ pool2,
        const float4* __restrict__ dt1, const int* __restrict__ rowptr,
        const int* __restrict__ cnt, const int* __restrict__ csr,
        const float* __restrict__ W1, const float* __restrict__ b1,
        float4* __restrict__ dt2) {
    int bx = blockIdx.x;
    if (bx < 1536) {
        dev_conv_h<32, 64, 331, 116, 36, 108, true>(bx & 511, bx >> 9, pool1, K2, cb2, pool2);
        return;
    }
    __shared__ float sW[16];
    if (threadIdx.x < 16) sW[threadIdx.x] = W1[threadIdx.x];
    __syncthreads();
    int n = (bx - 1536) * 256 + threadIdx.x;
    if (n >= NA) return;
    int cn = cnt[n];
    float dv = rsqrtf((float)cn + 1.0f);
    const int* row = csr + rowptr[n];
    float4 acc = dt1[n];
    int e = 0;
    for (; e + 3 < cn; e += 4) {
        int i0 = row[e], i1 = row[e + 1], i2 = row[e + 2], i3 = row[e + 3];
        float4 v0 = dt1[i0], v1 = dt1[i1], v2 = dt1[i2], v3 = dt1[i3];
        acc.x += (v0.x + v1.x) + (v2.x + v3.x);
        acc.y += (v0.y + v1.y) + (v2.y + v3.y);
        acc.z += (v0.z + v1.z) + (v2.z + v3.z);
        acc.w += (v0.w + v1.w) + (v2.w + v3.w);
    }
    for (; e < cn; e++) {
        float4 v = dt1[row[e]];
        acc.x += v.x; acc.y += v.y; acc.z += v.z; acc.w += v.w;
    }
    const float4 bq = *(const float4*)b1;
    float a[4] = {acc.x, acc.y, acc.z, acc.w};
    float bb[4] = {bq.x, bq.y, bq.z, bq.w};
    float o[4];
#pragma unroll
    for (int f = 0; f < 4; f++) {
        float s = 0.f;
#pragma unroll
        for (int k = 0; k < 4; k++) s = fmaf(a[k], sW[k * 4 + f], s);
        o[f] = dv * fmaxf(fmaf(dv, s, bb[f]), 0.f);   // dt2 = dv*relu(...)
    }
    dt2[n] = make_float4(o[0], o[1], o[2], o[3]);
}

// -------- K_C: conv3 dot2 (1024) || gather2+W2 -> dt3 fp16 (782) -----------
__global__ __launch_bounds__(256) void k_C(
        const __half* __restrict__ pool2, const float* __restrict__ K3,
        const float* __restrict__ cb3, float* __restrict__ pool3,
        const float4* __restrict__ dt2, const int* __restrict__ rowptr,
        const int* __restrict__ cnt, const int* __restrict__ csr,
        const float* __restrict__ W2, const float* __restrict__ b2,
        uint4* __restrict__ dt3) {
    int bx = blockIdx.x;
    if (bx < 1024) {
        dev_conv_h<64, 128, 108, 68, 20, 33, false>(bx & 511, bx >> 9, pool2, K3, cb3, pool3);
        return;
    }
    __shared__ float sW[32];
    if (threadIdx.x < 32) sW[threadIdx.x] = W2[threadIdx.x];
    __syncthreads();
    int n = (bx - 1024) * 256 + threadIdx.x;
    if (n >= NA) return;
    int cn = cnt[n];
    float dv = rsqrtf((float)cn + 1.0f);
    const int* row = csr + rowptr[n];
    float4 acc = dt2[n];
    int e = 0;
    for (; e + 3 < cn; e += 4) {
        int i0 = row[e], i1 = row[e + 1], i2 = row[e + 2], i3 = row[e + 3];
        float4 v0 = dt2[i0], v1 = dt2[i1], v2 = dt2[i2], v3 = dt2[i3];
        acc.x += (v0.x + v1.x) + (v2.x + v3.x);
        acc.y += (v0.y + v1.y) + (v2.y + v3.y);
        acc.z += (v0.z + v1.z) + (v2.z + v3.z);
        acc.w += (v0.w + v1.w) + (v2.w + v3.w);
    }
    for (; e < cn; e++) {
        float4 v = dt2[row[e]];
        acc.x += v.x; acc.y += v.y; acc.z += v.z; acc.w += v.w;
    }
    float a[4] = {acc.x, acc.y, acc.z, acc.w};
    float o[8];
#pragma unroll
    for (int f = 0; f < 8; f++) {
        float s = 0.f;
#pragma unroll
        for (int k = 0; k < 4; k++) s = fmaf(a[k], sW[k * 8 + f], s);
        o[f] = dv * fmaxf(fmaf(dv, s, b2[f]), 0.f);   // dt3 = dv*relu(...)
    }
    dt3[n] = make_uint4(f2h(o[0], o[1]), f2h(o[2], o[3]),
                        f2h(o[4], o[5]), f2h(o[6], o[7]));
}

// -------- K_D: gather3(fp16)+W3+segmax (782) || mean+Wxt -> cx (64) --------
__global__ __launch_bounds__(256) void k_D(
        const uint4* __restrict__ dt3, const int* __restrict__ rowptr,
        const int* __restrict__ cnt, const int* __restrict__ csr,
        const float* __restrict__ W3, const float* __restrict__ b3,
        const int* __restrict__ batch, unsigned* __restrict__ g,
        const float* __restrict__ pool3, const float* __restrict__ Wxt,
        const float* __restrict__ bxt, float* __restrict__ cx) {
    int bx = blockIdx.x;
    if (bx >= 782) {
        __shared__ float sa[8 * 128];
        int b0 = (bx - 782) * 8;
        for (int t = threadIdx.x; t < 8 * 128; t += 256) {
            int gg = t >> 7, k = t & 127;
            const float* r = pool3 + ((size_t)(b0 + gg) * 128 + k) * 33;
            float s = 0.f;
#pragma unroll
            for (int p = 0; p < 33; p++) s += r[p];
            sa[t] = s * (1.f / 33.f);
        }
        __syncthreads();
        int j = threadIdx.x;
        if (j >= 128) return;
        float bj = bxt[j];
        float acc[8];
#pragma unroll
        for (int gg = 0; gg < 8; gg++) acc[gg] = bj;
#pragma unroll 4
        for (int k = 0; k < 128; k++) {
            float w = Wxt[(size_t)k * 128 + j];
#pragma unroll
            for (int gg = 0; gg < 8; gg++) acc[gg] = fmaf(sa[gg * 128 + k], w, acc[gg]);
        }
#pragma unroll
        for (int gg = 0; gg < 8; gg++)
            cx[(size_t)(b0 + gg) * 128 + j] = fmaxf(acc[gg], 0.f);
        return;
    }
    __shared__ float sW[128];
    __shared__ unsigned sg[32];
    __shared__ int sbmin;
    int id = bx;
    if (threadIdx.x < 128) sW[threadIdx.x] = W3[threadIdx.x];
    if (threadIdx.x < 32) sg[threadIdx.x] = 0u;
    if (threadIdx.x == 0) sbmin = batch[id * 256];
    __syncthreads();
    int n = id * 256 + threadIdx.x;
    if (n < NA) {
        int cn = cnt[n];
        float dv = rsqrtf((float)cn + 1.0f);
        const int* row = csr + rowptr[n];
        uint4 sv = dt3[n];
        float4 lo = h4f(sv.x, sv.y), hi = h4f(sv.z, sv.w);
        float a0 = lo.x, a1 = lo.y, a2 = lo.z, a3 = lo.w;
        float a4 = hi.x, a5 = hi.y, a6 = hi.z, a7 = hi.w;
        int e = 0;
        for (; e + 3 < cn; e += 4) {
            uint4 p0 = dt3[row[e]],     p1 = dt3[row[e + 1]];
            uint4 p2 = dt3[row[e + 2]], p3 = dt3[row[e + 3]];
            float4 l0 = h4f(p0.x, p0.y), h0 = h4f(p0.z, p0.w);
            float4 l1 = h4f(p1.x, p1.y), h1 = h4f(p1.z, p1.w);
            float4 l2 = h4f(p2.x, p2.y), h2 = h4f(p2.z, p2.w);
            float4 l3 = h4f(p3.x, p3.y), h3v = h4f(p3.z, p3.w);
            a0 += (l0.x + l1.x) + (l2.x + l3.x);
            a1 += (l0.y + l1.y) + (l2.y + l3.y);
            a2 += (l0.z + l1.z) + (l2.z + l3.z);
            a3 += (l0.w + l1.w) + (l2.w + l3.w);
            a4 += (h0.x + h1.x) + (h2.x + h3v.x);
            a5 += (h0.y + h1.y) + (h2.y + h3v.y);
            a6 += (h0.z + h1.z) + (h2.z + h3v.z);
            a7 += (h0.w + h1.w) + (h2.w + h3v.w);
        }
        for (; e < cn; e++) {
            uint4 p = dt3[row[e]];
            float4 l = h4f(p.x, p.y), h = h4f(p.z, p.w);
            a0 += l.x; a1 += l.y; a2 += l.z; a3 += l.w;
            a4 += h.x; a5 += h.y; a6 += h.z; a7 += h.w;
        }
        float af[8] = {a0, a1, a2, a3, a4, a5, a6, a7};
        int rb = batch[n] - sbmin;
        if (rb > 1) rb = 1;
#pragma unroll
        for (int f = 0; f < 16; f++) {
            float s = 0.f;
#pragma unroll
            for (int k = 0; k < 8; k++) s = fmaf(af[k], sW[k * 16 + f], s);
            float r = fmaxf(fmaf(dv, s, b3[f]), 0.f);
            atomicMax(&sg[rb * 16 + f], __float_as_uint(r));
        }
    }
    __syncthreads();
    if (threadIdx.x < 32) {
        unsigned v = sg[threadIdx.x];
        int rb2 = threadIdx.x >> 4, f = threadIdx.x & 15;
        int bbn = sbmin + rb2;
        if (v != 0u && bbn < NB) atomicMax(&g[bbn * 16 + f], v);
    }
}

// -------- head: g@Wg1 -> gp1 (relu), 256 blocks ----------------------------
__global__ __launch_bounds__(256) void k_head_g(
        const float* __restrict__ g, const float* __restrict__ Wg1,
        const float* __restrict__ bg1, float* __restrict__ gp1) {
    __shared__ float sa[8 * 16];
    int bx = blockIdx.x;
    int b0 = (bx >> 2) * 8;
    if (threadIdx.x < 128)
        sa[threadIdx.x] = g[b0 * 16 + threadIdx.x];
    __syncthreads();
    int j = (bx & 3) * 256 + threadIdx.x;
    float bj = bg1[j];
    float acc[8];
#pragma unroll
    for (int gg = 0; gg < 8; gg++) acc[gg] = bj;
#pragma unroll
    for (int k = 0; k < 16; k++) {
        float w = Wg1[(size_t)k * 1024 + j];
#pragma unroll
        for (int gg = 0; gg < 8; gg++) acc[gg] = fmaf(sa[gg * 16 + k], w, acc[gg]);
    }
#pragma unroll
    for (int gg = 0; gg < 8; gg++)
        gp1[(size_t)(b0 + gg) * 1024 + j] = fmaxf(acc[gg], 0.f);
}

// -------- gvec += (gp1 K-slice)@Wg2 ; K-split x4, fp32 atomicAdd -----------
__global__ __launch_bounds__(256) void k_gvec_ks(
        const float* __restrict__ gp1, const float* __restrict__ Wg2,
        float* __restrict__ gvec) {
    __shared__ float sa[8 * 256];
    int k0 = blockIdx.x * 256;
    int b0 = blockIdx.y * 8;
    for (int t = threadIdx.x; t < 8 * 256; t += 256) {
        int gg = t >> 8, k = t & 255;
        sa[t] = gp1[(size_t)(b0 + gg) * 1024 + k0 + k];
    }
    __syncthreads();
    int j = threadIdx.x;
    if (j >= 128) return;
    float acc[8];
#pragma unroll
    for (int gg = 0; gg < 8; gg++) acc[gg] = 0.f;
#pragma unroll 4
    for (int k = 0; k < 256; k++) {
        float w = Wg2[(size_t)(k0 + k) * 128 + j];
#pragma unroll
        for (int gg = 0; gg < 8; gg++) acc[gg] = fmaf(sa[gg * 256 + k], w, acc[gg]);
    }
#pragma unroll
    for (int gg = 0; gg < 8; gg++)
        atomicAdd(&gvec[(size_t)(b0 + gg) * 128 + j], acc[gg]);
}

// -------- dense with concatenated input [gvec | cx] -> relu -> xf1 ---------
template<int KA, int KB2, int BGRP, bool RELU>
__global__ __launch_bounds__(256) void k_dense_cat_g(
        const float* __restrict__ A1, const float* __restrict__ A2,
        const float* __restrict__ W, const float* __restrict__ bias,
        float* __restrict__ out, int ncols) {
    constexpr int K = KA + KB2;
    __shared__ float sa[BGRP * K];
    int b0 = blockIdx.y * BGRP;
    for (int t = threadIdx.x; t < BGRP * K; t += 256) {
        int gg = t / K, k = t - gg * K;
        sa[t] = (k < KA) ? A1[(size_t)(b0 + gg) * KA + k]
                         : A2[(size_t)(b0 + gg) * KB2 + (k - KA)];
    }
    __syncthreads();
    int j = blockIdx.x * 256 + threadIdx.x;
    if (j >= ncols) return;
    float bj = bias[j];
    float acc[BGRP];
#pragma unroll
    for (int gg = 0; gg < BGRP; gg++) acc[gg] = bj;
#pragma unroll 4
    for (int k = 0; k < K; k++) {
        float w = W[(size_t)k * ncols + j];
#pragma unroll
        for (int gg = 0; gg < BGRP; gg++) acc[gg] = fmaf(sa[gg * K + k], w, acc[gg]);
    }
#pragma unroll
    for (int gg = 0; gg < BGRP; gg++) {
        float v = acc[gg];
        if (RELU) v = fmaxf(v, 0.f);
        out[(size_t)(b0 + gg) * ncols + j] = v;
    }
}

// -------- xf2 += (xf1 K-slice)@Wf2 ; K-split x2, j-split x2 ----------------
__global__ __launch_bounds__(256) void k_xf2_ks(
        const float* __restrict__ xf1, const float* __restrict__ Wf2,
        float* __restrict__ xf2) {
    __shared__ float sa[8 * 512];
    int jb = blockIdx.x & 1;
    int k0 = (blockIdx.x >> 1) * 512;
    int b0 = blockIdx.y * 8;
    for (int t = threadIdx.x; t < 8 * 512; t += 256) {
        int gg = t >> 9, k = t & 511;
        sa[t] = xf1[(size_t)(b0 + gg) * 1024 + k0 + k];
    }
    __syncthreads();
    int j = jb * 256 + threadIdx.x;
    float acc[8];
#pragma unroll
    for (int gg = 0; gg < 8; gg++) acc[gg] = 0.f;
#pragma unroll 4
    for (int k = 0; k < 512; k++) {
        float w = Wf2[(size_t)(k0 + k) * 512 + j];
#pragma unroll
        for (int gg = 0; gg < 8; gg++) acc[gg] = fmaf(sa[gg * 512 + k], w, acc[gg]);
    }
#pragma unroll
    for (int gg = 0; gg < 8; gg++)
        atomicAdd(&xf2[(size_t)(b0 + gg) * 512 + j], acc[gg]);
}

// final 512->2 layer; applies the deferred relu on xf2
__global__ __launch_bounds__(256) void k_dense_out(
        const float* __restrict__ A, const float* __restrict__ W,
        const float* __restrict__ bias, float* __restrict__ out) {
    int idx = blockIdx.x * 256 + threadIdx.x;
    if (idx >= NB * 2) return;
    int b = idx >> 1, j = idx & 1;
    float s = bias[j];
#pragma unroll 8
    for (int k = 0; k < 512; k++)
        s = fmaf(fmaxf(A[b * 512 + k], 0.f), W[k * 2 + j], s);
    out[idx] = s;
}

extern "C" void kernel_launch(void* const* d_in, const int* in_sizes, int n_in,
                              void* d_out, int out_size, void* d_ws, size_t ws_size,
                              hipStream_t stream) {
    (void)in_sizes; (void)n_in; (void)out_size; (void)ws_size;
    const float* x   = (const float*)d_in[0];
    const int*  ei   = (const int*)d_in[1];
    const int*  batch= (const int*)d_in[2];
    const float* tgt = (const float*)d_in[3];
    const float* W1  = (const float*)d_in[4];  const float* b1  = (const float*)d_in[5];
    const float* W2  = (const float*)d_in[6];  const float* b2  = (const float*)d_in[7];
    const float* W3  = (const float*)d_in[8];  const float* b3  = (const float*)d_in[9];
    const float* Wg1 = (const float*)d_in[10]; const float* bg1 = (const float*)d_in[11];
    const float* Wg2 = (const float*)d_in[12]; const float* bg2 = (const float*)d_in[13];
    const float* K1  = (const float*)d_in[14]; const float* cb1 = (const float*)d_in[15];
    const float* K2  = (const float*)d_in[16]; const float* cb2 = (const float*)d_in[17];
    const float* K3  = (const float*)d_in[18]; const float* cb3 = (const float*)d_in[19];
    const float* Wxt = (const float*)d_in[20]; const float* bxt = (const float*)d_in[21];
    const float* Wf1 = (const float*)d_in[22]; const float* bf1 = (const float*)d_in[23];
    const float* Wf2 = (const float*)d_in[24]; const float* bf2 = (const float*)d_in[25];
    const float* Wo  = (const float*)d_in[26]; const float* bo  = (const float*)d_in[27];
    const int* srcp = ei;        // edge_index[0]
    const int* dstp = ei + NE;   // edge_index[1]

    float* ws = (float*)d_ws;
    float4* dt1 = (float4*)ws; ws += (size_t)NA * 4;   // dis*x          (3.2 MB)
    float4* dt2 = (float4*)ws; ws += (size_t)NA * 4;   // dis*out1       (3.2 MB)
    uint4*  dt3 = (uint4*)ws;  ws += (size_t)NA * 4;   // dis*out2 fp16  (3.2 MB)
    float* g     = ws; ws += NB * 16;
    float* gp1   = ws; ws += NB * 1024;
    float* gvec  = ws; ws += NB * 128;
    float* cx    = ws; ws += NB * 128;
    float* xf1   = ws; ws += NB * 1024;
    float* xf2   = ws; ws += NB * 512;
    __half* pool1 = (__half*)ws; ws += (size_t)NB * 32 * 331;   // fp16 (half used)
    __half* pool2 = (__half*)ws; ws += (size_t)NB * 64 * 108;   // fp16
    float* pool3 = ws; ws += (size_t)NB * 128 * 33;             // fp32 (head)
    int*   cnt    = (int*)ws; ws += NA;
    int*   rowptr = (int*)ws; ws += NA;
    int*   csr    = (int*)ws; ws += NE;               // compact CSR
    int*   gcursor= (int*)ws; ws += NBKT;
    unsigned* stage = (unsigned*)ws; ws += (size_t)NBKT * BKTCAP; // 16.8 MB, OWN

    dim3 blk(256);

    k_init<<<1024, blk, 0, stream>>>((unsigned*)g, gcursor, gvec, bg2, xf2, bf2);
    // K_A: pass1 (1000) || conv1 oy=0 (512)
    k_A<<<1512, blk, 0, stream>>>(srcp, dstp, gcursor, stage, tgt, K1, cb1, pool1);
    // K_Bp: pass2 (256) || conv1 oy=1 (512)
    k_Bp<<<768, blk, 0, stream>>>(stage, gcursor, rowptr, cnt, csr, x, dt1,
                                  tgt, K1, cb1, pool1);
    // K_B: conv2 dot2 (1536) || gather1+W1 (782)
    k_B<<<2318, blk, 0, stream>>>(pool1, K2, cb2, pool2,
                                  dt1, rowptr, cnt, csr, W1, b1, dt2);
    // K_C: conv3 dot2 (1024) || gather2+W2 (782)
    k_C<<<1806, blk, 0, stream>>>(pool2, K3, cb3, pool3,
                                  dt2, rowptr, cnt, csr, W2, b2, dt3);
    // K_D: gather3(fp16)+W3+segmax (782) || mean+Wxt (64)
    k_D<<<846, blk, 0, stream>>>(dt3, rowptr, cnt, csr, W3, b3,
                                 batch, (unsigned*)g, pool3, Wxt, bxt, cx);

    // dense head (parallelism-first: every kernel >=256 blocks)
    k_head_g<<<256, blk, 0, stream>>>(g, Wg1, bg1, gp1);
    k_gvec_ks<<<dim3(4, 64), blk, 0, stream>>>(gp1, Wg2, gvec);
    k_dense_cat_g<128, 128, 8, true><<<dim3(4, 64), blk, 0, stream>>>(gvec, cx, Wf1, bf1, xf1, 1024);
    k_xf2_ks<<<dim3(4, 64), blk, 0, stream>>>(xf1, Wf2, xf2);
    k_dense_out<<<4, blk, 0, stream>>>(xf2, Wo, bo, (float*)d_out);
}